// Round 7
// baseline (592.781 us; speedup 1.0000x reference)
//
#include <hip/hip_runtime.h>

typedef unsigned short u16;
typedef unsigned int u32;
typedef __bf16 bf16x8 __attribute__((ext_vector_type(8)));
typedef _Float16 f16;
typedef _Float16 f16x8 __attribute__((ext_vector_type(8)));
typedef float f32x4 __attribute__((ext_vector_type(4)));
typedef float f32x16 __attribute__((ext_vector_type(16)));

#define B_ 2
#define N_ 65536
#define M_ 16384
#define C1_ 128
#define C2_ 256
#define K1_ 384   // C1+C2
#define O1_ 256   // mlp[1]
#define O2_ 128   // mlp[2]
#define JT_ 512       // 32-wide j-tiles per batch (M_/32)
#define HT_ (JT_/2)   // j-tiles per half = 256
// Keys are scaled by S^2 = 65536 (S=256 folded into the f16 splits). Scaling
// keeps every split residual in the f16 NORMAL range, killing the denormal-
// flush term that forced the old 6e-3 slack. Worst-case |key/S^2 - (d-u2)|:
// dropped lo*lo cross terms ~1.6e-4 + MFMA fp32 accum ~2e-4 + misc ~1e-4
// => 2eps ~ 1.0e-3. EPS2_ = 2e-3 * S^2 (2x worst-case margin, ~60x realistic).
#define EPS2_ 131.072f
#define TFIN_ 8.0f    // scaled (1.2e-4 unscaled) threshold-fold inflation

__device__ __forceinline__ u16 f2bf(float f) {
    u32 u = __float_as_uint(f);
    u32 r = (u + 0x7FFFu + ((u >> 16) & 1u)) >> 16;   // RNE
    return (u16)r;
}
__device__ __forceinline__ float bf2f(u16 h) {
    return __uint_as_float(((u32)h) << 16);
}
__device__ __forceinline__ u32 pack2(float lo, float hi) {
    return (u32)f2bf(lo) | ((u32)f2bf(hi) << 16);
}
__device__ __forceinline__ uint4 pack8(float4 a, float4 b) {
    uint4 r;
    r.x = pack2(a.x, a.y); r.y = pack2(a.z, a.w);
    r.z = pack2(b.x, b.y); r.w = pack2(b.z, b.w);
    return r;
}
__device__ __forceinline__ u16 h2u(f16 h) {
    union { f16 h; u16 u; } c; c.h = h; return c.u;
}

// Exact-IEEE fp32 mul with an optimization barrier so the backend can NEVER
// contract it into an FMA (HIP default is -ffp-contract=fast).
__device__ __forceinline__ float mul_rn(float a, float b) {
    float p = __fmul_rn(a, b);
    asm volatile("" : "+v"(p));
    return p;
}
// u2/k2: elementwise-square (each product rounded) + ascending reduce
__device__ __forceinline__ float sq3_np(float x, float y, float z) {
    return __fadd_rn(__fadd_rn(mul_rn(x, x), mul_rn(y, y)), mul_rn(z, z));
}
// Eigen/XLA gebp K=3 dot: ascending k, FMA accumulate into rounded first product
__device__ __forceinline__ float dot3_fma(float a0, float b0, float a1, float b1,
                                          float a2, float b2) {
    return fmaf(a2, b2, fmaf(a1, b1, mul_rn(a0, b0)));
}

// ============================== NN search: 32x32x16 MFMA filter + exact refine
// SCALED key: key_ij = S^2*(k2_j - 2*dot_ij) via mfma_f32_32x32x16_f16.
// K-slots: 0-8 split coords (A = split(-512x), B = split(256k): hh, h*l, l*h),
// 9-10 k2 (A=256, B=split(256*k2)), 11-12 pass-B threshold fold
// (A=split(-(thr+TFIN_)/256), B=256) => MFMA emits key - (thr+TFIN_), all
// scaled. thr' > thr strictly => every certified-needed candidate is <= 0
// => group-min sign test; exact refine (raw f32 data, reference-rounded)
// reproduces the reference argmin bit-exactly. j halves merged as before.

__global__ __launch_bounds__(256) void k_prep_u(const float* __restrict__ unk,
                                                u16* __restrict__ Aprep) {
    int g = blockIdx.x * 256 + threadIdx.x;          // over B*N
    const float* up = unk + (size_t)g * 3;
    float tx = -512.f * up[0], ty = -512.f * up[1], tz = -512.f * up[2];
    f16 xh = (f16)tx; f16 xl = (f16)(tx - (float)xh);
    f16 yh = (f16)ty; f16 yl = (f16)(ty - (float)yh);
    f16 zh = (f16)tz; f16 zl = (f16)(tz - (float)zh);
    u16 lo[8] = {h2u(xh), h2u(xh), h2u(xl), h2u(yh), h2u(yh), h2u(yl), h2u(zh), h2u(zh)};
    u16 hi[8] = {h2u(zl), 0x5C00u, 0x5C00u, 0, 0, 0, 0, 0};   // 256.0 f16
    u16* tb = Aprep + ((size_t)(g >> 5)) * 512;      // tile = 64 lanes * 8 u16
    int r = g & 31;
    *(uint4*)(tb + r * 8) = *(uint4*)lo;
    *(uint4*)(tb + (r + 32) * 8) = *(uint4*)hi;
}

__global__ __launch_bounds__(256) void k_prep_k(const float* __restrict__ kn,
                                                u16* __restrict__ Bprep,
                                                float4* __restrict__ kco) {
    int g = blockIdx.x * 256 + threadIdx.x;          // over B*M
    const float* kp = kn + (size_t)g * 3;
    float x = kp[0], y = kp[1], z = kp[2];
    float qv = sq3_np(x, y, z);                       // EXACT ref k2 sequence
    float sx = 256.f * x, sy = 256.f * y, sz = 256.f * z, sq = 256.f * qv;
    f16 xh = (f16)sx; f16 xl = (f16)(sx - (float)xh);
    f16 yh = (f16)sy; f16 yl = (f16)(sy - (float)yh);
    f16 zh = (f16)sz; f16 zl = (f16)(sz - (float)zh);
    f16 qh = (f16)sq; f16 ql = (f16)(sq - (float)qh);
    u16 lo[8] = {h2u(xh), h2u(xl), h2u(xh), h2u(yh), h2u(yl), h2u(yh), h2u(zh), h2u(zl)};
    // slots 11,12 = 256.0 so pass B's A-side -(thr)/256 split rides the MFMA
    u16 hi[8] = {h2u(zh), h2u(qh), h2u(ql), 0x5C00u, 0x5C00u, 0, 0, 0};
    u16* tb = Bprep + ((size_t)(g >> 5)) * 512;
    int r = g & 31;
    *(uint4*)(tb + r * 8) = *(uint4*)lo;
    *(uint4*)(tb + (r + 32) * 8) = *(uint4*)hi;
    kco[g] = make_float4(x, y, z, qv);
}

__global__ __launch_bounds__(256, 4) void k_nn(
        const u16* __restrict__ Aprep, const u16* __restrict__ Bprep,
        const float* __restrict__ unk, const float4* __restrict__ kco,
        unsigned long long* __restrict__ pc) {
    __shared__ unsigned long long cand[256];   // wave-private 64-row slices
    __shared__ float thrS[256];                // wave-private 64-row slices
    const int t = threadIdx.x;
    const int half = blockIdx.y, b = blockIdx.z;
    const int lane = t & 63, w = t >> 6;
    const int rowbase = blockIdx.x * 256;            // 256 rows per block
    // wave w owns rows [rowbase + w*64, +64) = two 32-row tiles
    const u16* at = Aprep + (((size_t)(b * N_ + rowbase + w * 64)) >> 5) * 512;
    f16x8 af0 = *(const f16x8*)(at + lane * 8);
    f16x8 af1 = *(const f16x8*)(at + 512 + lane * 8);
    const u16* Bp = Bprep + ((size_t)b * JT_ + (size_t)half * HT_) * 512 + lane * 8;
    cand[t] = ~0ULL;

    const f32x16 zz = {0.f,0.f,0.f,0.f,0.f,0.f,0.f,0.f,0.f,0.f,0.f,0.f,0.f,0.f,0.f,0.f};

    // ---------------- pass A: rowmin over this j-half (no barriers) ---------
    f32x16 rm0, rm1;
#pragma unroll
    for (int r = 0; r < 16; ++r) { rm0[r] = 3.4e38f; rm1[r] = 3.4e38f; }

    // 2-tile-ahead rotation; final prefetch reads <=2 KB past this half
    // (next half / kco region -- mapped workspace, values unused).
    f16x8 c0 = *(const f16x8*)Bp;
    f16x8 c1 = *(const f16x8*)(Bp + 512);
    for (int tp = 0; tp < HT_; tp += 2) {
        f16x8 n0 = *(const f16x8*)(Bp + 1024);
        f16x8 n1 = *(const f16x8*)(Bp + 1536);
        Bp += 1024;
        f32x16 a  = __builtin_amdgcn_mfma_f32_32x32x16_f16(af0, c0, zz, 0, 0, 0);
        f32x16 ca = __builtin_amdgcn_mfma_f32_32x32x16_f16(af0, c1, zz, 0, 0, 0);
#pragma unroll
        for (int r = 0; r < 16; ++r)
            rm0[r] = fminf(fminf(rm0[r], a[r]), ca[r]);
        a  = __builtin_amdgcn_mfma_f32_32x32x16_f16(af1, c0, zz, 0, 0, 0);
        ca = __builtin_amdgcn_mfma_f32_32x32x16_f16(af1, c1, zz, 0, 0, 0);
#pragma unroll
        for (int r = 0; r < 16; ++r)
            rm1[r] = fminf(fminf(rm1[r], a[r]), ca[r]);
        c0 = n0; c1 = n1;
    }

    // reduce over the 32 cols -> per-row thresholds (wave-private LDS slice)
#pragma unroll
    for (int r = 0; r < 16; ++r) {
        float v0 = rm0[r], v1 = rm1[r];
        v0 = fminf(v0, __shfl_xor(v0, 1));  v1 = fminf(v1, __shfl_xor(v1, 1));
        v0 = fminf(v0, __shfl_xor(v0, 2));  v1 = fminf(v1, __shfl_xor(v1, 2));
        v0 = fminf(v0, __shfl_xor(v0, 4));  v1 = fminf(v1, __shfl_xor(v1, 4));
        v0 = fminf(v0, __shfl_xor(v0, 8));  v1 = fminf(v1, __shfl_xor(v1, 8));
        v0 = fminf(v0, __shfl_xor(v0, 16)); v1 = fminf(v1, __shfl_xor(v1, 16));
        if ((lane & 31) == 0) {
            int rl = w * 64 + ((lane >> 5) << 2) + (r & 3) + 8 * (r >> 2);
            thrS[rl] = v0 + EPS2_;
            thrS[rl + 32] = v1 + EPS2_;
        }
    }
    // patch A fragments: k-slots 11,12 (lanes>=32, elems 3,4) =
    // split(-(thr+TFIN_)/256); product with B slots (=256) gives -(thr+TFIN_)
    // (same-wave LDS RAW -> compiler-inserted lgkmcnt wait; no barrier needed)
    if (lane >= 32) {
        float tf0 = (thrS[w * 64 + (lane & 31)] + TFIN_) * 0.00390625f;
        f16 h0 = (f16)(-tf0);
        af0[3] = h0; af0[4] = (f16)(-tf0 - (float)h0);
        float tf1 = (thrS[w * 64 + 32 + (lane & 31)] + TFIN_) * 0.00390625f;
        f16 h1 = (f16)(-tf1);
        af1[3] = h1; af1[4] = (f16)(-tf1 - (float)h1);
    }

    // ---------------- pass B: exact refine (MFMA emits key - thr') ----------
    const float4* kcb = kco + (size_t)b * M_;
    const float* ub = unk + (size_t)b * N_ * 3;
    const int rloc0 = w * 64 + ((lane >> 5) << 2);   // + rr + 8*g  [+32 rt1]
    const int jb0 = half * (M_ / 2);

#define REFINE(RL, AV)                                                         \
    if ((AV) <= 0.f) {                                                         \
        int rl = (RL);                                                         \
        const float* up = ub + (size_t)(rowbase + rl) * 3;                     \
        float x = up[0], y = up[1], zc = up[2];                                \
        float uq = sq3_np(x, y, zc);                                           \
        float dot = dot3_fma(x, kc.x, y, kc.y, zc, kc.z);                      \
        float d = __fadd_rn(fmaf(-2.0f, dot, uq), kc.w);                       \
        u32 db = __float_as_uint(d);                                           \
        db = (db & 0x80000000u) ? ~db : (db | 0x80000000u);                    \
        atomicMin(&cand[rl], ((unsigned long long)db << 32) | (u32)j);         \
    }

    Bp -= (size_t)HT_ * 512;                         // rewind to half start
    c0 = *(const f16x8*)Bp;
    f16x8 c1b = *(const f16x8*)(Bp + 512);
    for (int tt = 0; tt < HT_; ++tt) {
        f16x8 nx = *(const f16x8*)(Bp + 1024);
        Bp += 512;
        f32x16 a0 = __builtin_amdgcn_mfma_f32_32x32x16_f16(af0, c0, zz, 0, 0, 0);
        f32x16 a1 = __builtin_amdgcn_mfma_f32_32x32x16_f16(af1, c0, zz, 0, 0, 0);
        // hierarchical sign test: 8 group-mins (4 r's each) -> global ballot
        float gm0[4], gm1[4];
#pragma unroll
        for (int g = 0; g < 4; ++g) {
            gm0[g] = fminf(fminf(a0[4*g], a0[4*g+1]), fminf(a0[4*g+2], a0[4*g+3]));
            gm1[g] = fminf(fminf(a1[4*g], a1[4*g+1]), fminf(a1[4*g+2], a1[4*g+3]));
        }
        float gall = fminf(fminf(fminf(gm0[0], gm0[1]), fminf(gm0[2], gm0[3])),
                           fminf(fminf(gm1[0], gm1[1]), fminf(gm1[2], gm1[3])));
        if (__ballot(gall <= 0.f)) {                 // ~30% of tiles
            int j = jb0 + tt * 32 + (lane & 31);
            float4 kc = kcb[j];
#pragma unroll
            for (int g = 0; g < 4; ++g) {
                if (__any(gm0[g] <= 0.f)) {
#pragma unroll
                    for (int rr = 0; rr < 4; ++rr)
                        REFINE(rloc0 + 8 * g + rr, a0[4*g+rr])
                }
                if (__any(gm1[g] <= 0.f)) {
#pragma unroll
                    for (int rr = 0; rr < 4; ++rr)
                        REFINE(rloc0 + 32 + 8 * g + rr, a1[4*g+rr])
                }
            }
        }
        c0 = c1b; c1b = nx;
    }
#undef REFINE
    // cand[t] belongs to wave t>>6 (rows are wave-local) -> no barrier
    pc[((size_t)(half * B_ + b)) * N_ + rowbase + t] = cand[t];
}

// merge the two j-half packed mins; lower half has smaller j => tie-break ok
__global__ __launch_bounds__(256) void k_nn_merge(
        const unsigned long long* __restrict__ pc, int* __restrict__ idx) {
    int g = blockIdx.x * 256 + threadIdx.x;          // over B*N
    unsigned long long a = pc[g];
    unsigned long long c = pc[(size_t)(B_ * N_) + g];
    idx[g] = (int)(u32)((c < a ? c : a) & 0xFFFFFFFFu);
}

// ------------------------------------------- transpose known_feats -> (b,m,c) bf16
__global__ __launch_bounds__(256) void k_tr_kf(const float* __restrict__ kf,
                                               u16* __restrict__ kfT) {
    __shared__ float lt[64][65];
    const int t = threadIdx.x, b = blockIdx.z;
    const int j0 = blockIdx.x * 64, c0 = blockIdx.y * 64;
    const int jl = t & 63, cl4 = t >> 6;
#pragma unroll
    for (int p = 0; p < 16; ++p) {
        int c = c0 + cl4 + p * 4;
        lt[cl4 + p * 4][jl] = kf[((size_t)(b * C2_ + c)) * M_ + j0 + jl];
    }
    __syncthreads();
    const int cl = t & 63, jr4 = t >> 6;
#pragma unroll
    for (int p = 0; p < 16; ++p) {
        int j = j0 + jr4 + p * 4;
        kfT[((size_t)(b * M_ + j)) * C2_ + c0 + cl] = f2bf(lt[cl][jr4 + p * 4]);
    }
}

// ------------------------------- transpose unknow_feats into newF[...,256:384) bf16
__global__ __launch_bounds__(256) void k_tr_uf(const float* __restrict__ uf,
                                               u16* __restrict__ newF) {
    __shared__ float lt[64][65];
    const int t = threadIdx.x, b = blockIdx.z;
    const int i0 = blockIdx.x * 64, c0 = blockIdx.y * 64;
    const int il = t & 63, cl4 = t >> 6;
#pragma unroll
    for (int p = 0; p < 16; ++p) {
        int c = c0 + cl4 + p * 4;
        lt[cl4 + p * 4][il] = uf[((size_t)(b * C1_ + c)) * N_ + i0 + il];
    }
    __syncthreads();
    const int cl = t & 63, ir4 = t >> 6;
#pragma unroll
    for (int p = 0; p < 16; ++p) {
        int i = i0 + ir4 + p * 4;
        newF[((size_t)(b * N_ + i)) * K1_ + C2_ + c0 + cl] = f2bf(lt[cl][ir4 + p * 4]);
    }
}

// ------------------------------------ gather kfT rows into newF[...,0:256) (dense)
__global__ __launch_bounds__(256) void k_gather(const u16* __restrict__ kfT,
                                                const int* __restrict__ idx,
                                                u16* __restrict__ newF) {
    const int t = threadIdx.x, b = blockIdx.y;
    const int il = t >> 5, qq = t & 31;
    const int i = blockIdx.x * 8 + il;
    const int j = idx[b * N_ + i];
    const uint4* src = (const uint4*)(kfT + ((size_t)(b * M_ + j)) * C2_) + qq;
    uint4* dst = (uint4*)(newF + ((size_t)(b * N_ + i)) * K1_) + qq;
    *dst = *src;
}

// ---------------------------------------------------------------- GEMM1
// y1[b][i][o] (bf16) = newF[b][i][:] . w1[o][:]   tiles 128x128, BK=32
// BN1 stats fused in epilogue (on the bf16-rounded values, == old k_stats_bf16)
__global__ __launch_bounds__(256) void k_gemm1(const u16* __restrict__ newF,
                                               const float* __restrict__ w1,
                                               u16* __restrict__ y1,
                                               float* __restrict__ bsum,
                                               float* __restrict__ bsq) {
    __shared__ u16 As[128 * 40];
    __shared__ u16 Bs[128 * 40];
    const int t = threadIdx.x, b = blockIdx.z;
    const int i0 = blockIdx.x * 128, o0 = blockIdx.y * 128;
    const int lane = t & 63, wv = t >> 6, wr = wv >> 1, wc = wv & 1;
    const int col = lane & 15, q = lane >> 4;

    const int rA0 = t >> 2, sA0 = t & 3;   // +256 => row+64, same sub
    const u16* aS0 = newF + ((size_t)(b * N_ + i0 + rA0)) * K1_ + sA0 * 8;
    const u16* aS1 = aS0 + (size_t)64 * K1_;
    const float* bS0 = w1 + (size_t)(o0 + rA0) * K1_ + sA0 * 8;
    const float* bS1 = bS0 + (size_t)64 * K1_;
    u16* aD0 = &As[rA0 * 40 + sA0 * 8];
    u16* aD1 = aD0 + 64 * 40;
    u16* bD0 = &Bs[rA0 * 40 + sA0 * 8];
    u16* bD1 = bD0 + 64 * 40;

    f32x4 acc[4][4];
#pragma unroll
    for (int m = 0; m < 4; ++m)
#pragma unroll
        for (int n = 0; n < 4; ++n) acc[m][n] = (f32x4){0.f, 0.f, 0.f, 0.f};

    uint4 a0 = *(const uint4*)aS0, a1 = *(const uint4*)aS1;
    float4 f00 = *(const float4*)bS0, f01 = *(const float4*)(bS0 + 4);
    float4 f10 = *(const float4*)bS1, f11 = *(const float4*)(bS1 + 4);

    for (int ks = 0; ks < 12; ++ks) {
        __syncthreads();
        *(uint4*)aD0 = a0; *(uint4*)aD1 = a1;
        *(uint4*)bD0 = pack8(f00, f01); *(uint4*)bD1 = pack8(f10, f11);
        __syncthreads();
        if (ks < 11) {
            int ko = (ks + 1) * 32;
            a0 = *(const uint4*)(aS0 + ko); a1 = *(const uint4*)(aS1 + ko);
            f00 = *(const float4*)(bS0 + ko); f01 = *(const float4*)(bS0 + ko + 4);
            f10 = *(const float4*)(bS1 + ko); f11 = *(const float4*)(bS1 + ko + 4);
        }
        const u16* ap = &As[(wr * 64 + col) * 40 + q * 8];
        const u16* bp = &Bs[(wc * 64 + col) * 40 + q * 8];
        bf16x8 af[4], bfr[4];
#pragma unroll
        for (int m = 0; m < 4; ++m) af[m] = *(const bf16x8*)(ap + m * 640);
#pragma unroll
        for (int n = 0; n < 4; ++n) bfr[n] = *(const bf16x8*)(bp + n * 640);
#pragma unroll
        for (int m = 0; m < 4; ++m)
#pragma unroll
            for (int n = 0; n < 4; ++n)
                acc[m][n] = __builtin_amdgcn_mfma_f32_16x16x32_bf16(af[m], bfr[n], acc[m][n], 0, 0, 0);
    }
    float ssum[4], ssq[4];
#pragma unroll
    for (int n = 0; n < 4; ++n) { ssum[n] = 0.f; ssq[n] = 0.f; }
#pragma unroll
    for (int m = 0; m < 4; ++m)
#pragma unroll
        for (int n = 0; n < 4; ++n) {
            int go = o0 + wc * 64 + n * 16 + col;
#pragma unroll
            for (int r = 0; r < 4; ++r) {
                int gi = i0 + wr * 64 + m * 16 + q * 4 + r;
                u16 hv = f2bf(acc[m][n][r]);
                y1[((size_t)(b * N_ + gi)) * O1_ + go] = hv;
                float v = bf2f(hv);
                ssum[n] += v; ssq[n] = fmaf(v, v, ssq[n]);
            }
        }
#pragma unroll
    for (int n = 0; n < 4; ++n) {
        float s = ssum[n], qv = ssq[n];
        s += __shfl_xor(s, 16); qv += __shfl_xor(qv, 16);
        s += __shfl_xor(s, 32); qv += __shfl_xor(qv, 32);
        if (q == 0) {
            int go = o0 + wc * 64 + n * 16 + col;
            atomicAdd(&bsum[go], s);
            atomicAdd(&bsq[go], qv);
        }
    }
}

__global__ void k_bn_fin(const float* __restrict__ sum, const float* __restrict__ sq,
                         const float* __restrict__ gamma, const float* __restrict__ beta,
                         float* __restrict__ scale, float* __restrict__ bias,
                         int C, float invN) {
    int t = threadIdx.x;
    if (t < C) {
        float mean = sum[t] * invN;
        float var = sq[t] * invN - mean * mean;
        float rs = rsqrtf(var + 1e-5f);
        float sc = gamma[t] * rs;
        scale[t] = sc;
        bias[t] = beta[t] - mean * sc;
    }
}

// ---------------------------------------------------------------- GEMM2
// y2[b][i][o] (f32) = relu(bn1(y1))[b][i][:] . w2[o][:]  (BN1 fused in A-staging)
// BN2 stats fused in epilogue (on the raw f32 values, == old k_stats_f32)
__global__ __launch_bounds__(256) void k_gemm2(const u16* __restrict__ y1,
                                               const float* __restrict__ w2,
                                               const float* __restrict__ s1,
                                               const float* __restrict__ b1,
                                               float* __restrict__ y2,
                                               float* __restrict__ bsum,
                                               float* __restrict__ bsq) {
    __shared__ u16 As[128 * 40];
    __shared__ u16 Bs[128 * 40];
    const int t = threadIdx.x, b = blockIdx.z;
    const int i0 = blockIdx.x * 128;
    const int lane = t & 63, wv = t >> 6, wr = wv >> 1, wc = wv & 1;
    const int col = lane & 15, q = lane >> 4;

    const int rA0 = t >> 2, sA0 = t & 3;
    const u16* aS0 = y1 + ((size_t)(b * N_ + i0 + rA0)) * O1_ + sA0 * 8;
    const u16* aS1 = aS0 + (size_t)64 * O1_;
    const float* bS0 = w2 + (size_t)rA0 * O1_ + sA0 * 8;
    const float* bS1 = bS0 + (size_t)64 * O1_;
    u16* aD0 = &As[rA0 * 40 + sA0 * 8];
    u16* aD1 = aD0 + 64 * 40;
    u16* bD0 = &Bs[rA0 * 40 + sA0 * 8];
    u16* bD1 = bD0 + 64 * 40;

    f32x4 acc[4][4];
#pragma unroll
    for (int m = 0; m < 4; ++m)
#pragma unroll
        for (int n = 0; n < 4; ++n) acc[m][n] = (f32x4){0.f, 0.f, 0.f, 0.f};

    uint4 a0 = *(const uint4*)aS0, a1 = *(const uint4*)aS1;
    float4 f00 = *(const float4*)bS0, f01 = *(const float4*)(bS0 + 4);
    float4 f10 = *(const float4*)bS1, f11 = *(const float4*)(bS1 + 4);

    for (int ks = 0; ks < 8; ++ks) {
        int oc = ks * 32 + sA0 * 8;
        float4 sc0 = *(const float4*)(s1 + oc), sc1 = *(const float4*)(s1 + oc + 4);
        float4 bb0 = *(const float4*)(b1 + oc), bb1 = *(const float4*)(b1 + oc + 4);
        uint4 h0, h1;
        {
            const u16* hs = (const u16*)&a0;
            float v[8];
            v[0] = fmaxf(fmaf(bf2f(hs[0]), sc0.x, bb0.x), 0.f);
            v[1] = fmaxf(fmaf(bf2f(hs[1]), sc0.y, bb0.y), 0.f);
            v[2] = fmaxf(fmaf(bf2f(hs[2]), sc0.z, bb0.z), 0.f);
            v[3] = fmaxf(fmaf(bf2f(hs[3]), sc0.w, bb0.w), 0.f);
            v[4] = fmaxf(fmaf(bf2f(hs[4]), sc1.x, bb1.x), 0.f);
            v[5] = fmaxf(fmaf(bf2f(hs[5]), sc1.y, bb1.y), 0.f);
            v[6] = fmaxf(fmaf(bf2f(hs[6]), sc1.z, bb1.z), 0.f);
            v[7] = fmaxf(fmaf(bf2f(hs[7]), sc1.w, bb1.w), 0.f);
            h0.x = pack2(v[0], v[1]); h0.y = pack2(v[2], v[3]);
            h0.z = pack2(v[4], v[5]); h0.w = pack2(v[6], v[7]);
        }
        {
            const u16* hs = (const u16*)&a1;
            float v[8];
            v[0] = fmaxf(fmaf(bf2f(hs[0]), sc0.x, bb0.x), 0.f);
            v[1] = fmaxf(fmaf(bf2f(hs[1]), sc0.y, bb0.y), 0.f);
            v[2] = fmaxf(fmaf(bf2f(hs[2]), sc0.z, bb0.z), 0.f);
            v[3] = fmaxf(fmaf(bf2f(hs[3]), sc0.w, bb0.w), 0.f);
            v[4] = fmaxf(fmaf(bf2f(hs[4]), sc1.x, bb1.x), 0.f);
            v[5] = fmaxf(fmaf(bf2f(hs[5]), sc1.y, bb1.y), 0.f);
            v[6] = fmaxf(fmaf(bf2f(hs[6]), sc1.z, bb1.z), 0.f);
            v[7] = fmaxf(fmaf(bf2f(hs[7]), sc1.w, bb1.w), 0.f);
            h1.x = pack2(v[0], v[1]); h1.y = pack2(v[2], v[3]);
            h1.z = pack2(v[4], v[5]); h1.w = pack2(v[6], v[7]);
        }
        __syncthreads();
        *(uint4*)aD0 = h0; *(uint4*)aD1 = h1;
        *(uint4*)bD0 = pack8(f00, f01); *(uint4*)bD1 = pack8(f10, f11);
        __syncthreads();
        if (ks < 7) {
            int ko = (ks + 1) * 32;
            a0 = *(const uint4*)(aS0 + ko); a1 = *(const uint4*)(aS1 + ko);
            f00 = *(const float4*)(bS0 + ko); f01 = *(const float4*)(bS0 + ko + 4);
            f10 = *(const float4*)(bS1 + ko); f11 = *(const float4*)(bS1 + ko + 4);
        }
        const u16* ap = &As[(wr * 64 + col) * 40 + q * 8];
        const u16* bp = &Bs[(wc * 64 + col) * 40 + q * 8];
        bf16x8 af[4], bfr[4];
#pragma unroll
        for (int m = 0; m < 4; ++m) af[m] = *(const bf16x8*)(ap + m * 640);
#pragma unroll
        for (int n = 0; n < 4; ++n) bfr[n] = *(const bf16x8*)(bp + n * 640);
#pragma unroll
        for (int m = 0; m < 4; ++m)
#pragma unroll
            for (int n = 0; n < 4; ++n)
                acc[m][n] = __builtin_amdgcn_mfma_f32_16x16x32_bf16(af[m], bfr[n], acc[m][n], 0, 0, 0);
    }
    float ssum[4], ssq[4];
#pragma unroll
    for (int n = 0; n < 4; ++n) { ssum[n] = 0.f; ssq[n] = 0.f; }
#pragma unroll
    for (int m = 0; m < 4; ++m)
#pragma unroll
        for (int n = 0; n < 4; ++n) {
            int go = wc * 64 + n * 16 + col;
#pragma unroll
            for (int r = 0; r < 4; ++r) {
                int gi = i0 + wr * 64 + m * 16 + q * 4 + r;
                float v = acc[m][n][r];
                y2[((size_t)(b * N_ + gi)) * O2_ + go] = v;
                ssum[n] += v; ssq[n] = fmaf(v, v, ssq[n]);
            }
        }
#pragma unroll
    for (int n = 0; n < 4; ++n) {
        float s = ssum[n], qv = ssq[n];
        s += __shfl_xor(s, 16); qv += __shfl_xor(qv, 16);
        s += __shfl_xor(s, 32); qv += __shfl_xor(qv, 32);
        if (q == 0) {
            int go = wc * 64 + n * 16 + col;
            atomicAdd(&bsum[go], s);
            atomicAdd(&bsq[go], qv);
        }
    }
}

// ---------------------------- BN2 affine + ReLU + transpose (b,i,o)->(b,o,i) out
__global__ __launch_bounds__(256) void k_out(const float* __restrict__ y2,
                                             const float* __restrict__ s2,
                                             const float* __restrict__ b2,
                                             float* __restrict__ out) {
    __shared__ float lt[64 * 65];
    const int t = threadIdx.x, b = blockIdx.z;
    const int i0 = blockIdx.x * 64, o0 = blockIdx.y * 64;
    const int oc = t & 63, ir4 = t >> 6;
    const float sc = s2[o0 + oc], bs = b2[o0 + oc];
#pragma unroll
    for (int p = 0; p < 16; ++p) {
        int i = i0 + ir4 + p * 4;
        float v = y2[((size_t)(b * N_ + i)) * O2_ + o0 + oc];
        lt[oc * 65 + ir4 + p * 4] = fmaxf(fmaf(v, sc, bs), 0.f);
    }
    __syncthreads();
    const int il = t & 63, or4 = t >> 6;
#pragma unroll
    for (int p = 0; p < 16; ++p) {
        int o = o0 + or4 + p * 4;
        out[((size_t)(b * O2_ + o)) * N_ + i0 + il] = lt[(or4 + p * 4) * 65 + il];
    }
}

extern "C" void kernel_launch(void* const* d_in, const int* in_sizes, int n_in,
                              void* d_out, int out_size, void* d_ws, size_t ws_size,
                              hipStream_t stream) {
    const float* unknown = (const float*)d_in[0];
    const float* known   = (const float*)d_in[1];
    const float* uf      = (const float*)d_in[2];
    const float* kf      = (const float*)d_in[3];
    const float* w1      = (const float*)d_in[4];
    const float* g1      = (const float*)d_in[5];
    const float* be1     = (const float*)d_in[6];
    const float* w2      = (const float*)d_in[7];
    const float* g2      = (const float*)d_in[8];
    const float* be2     = (const float*)d_in[9];
    float* out = (float*)d_out;

    char* w = (char*)d_ws;
    // stats block (zeroed each call): bn1_sum[256] bn1_sq[256] bn2_sum[128] bn2_sq[128]
    float* bn1_sum = (float*)w;
    float* bn1_sq  = bn1_sum + 256;
    float* bn2_sum = bn1_sq + 256;
    float* bn2_sq  = bn2_sum + 128;
    float* s1 = (float*)(w + 4096);     // 256
    float* b1 = s1 + 256;               // 256
    float* s2 = b1 + 256;               // 128
    float* b2 = s2 + 128;               // 128
    int* idx = (int*)(w + 8192);                        // 512 KiB
    u16* newF = (u16*)(w + 532480);                     // (B,n,384) bf16 = 100.7 MB
    float* y2 = (float*)(w + 532480);                   // alias (newF dead by GEMM2)
    size_t R2 = 532480 + 100663296ULL;
    // NN scratch (dead before y1 is written):
    u16*   Aprep = (u16*)(w + R2);                      // 4 MiB (4096 tiles * 1KB)
    u16*   Bprep = (u16*)(w + R2 + 4194304ULL);         // 1 MiB (1024 tiles * 1KB)
    float4* kco  = (float4*)(w + R2 + 5242880ULL);      // 512 KiB
    unsigned long long* pc = (unsigned long long*)(w + R2 + 5767168ULL); // 2 MiB
    u16*  kfT = (u16*)(w + R2 + 16777216ULL);           // 16.7MB (dead before y1)
    u16*   y1 = (u16*)(w + R2);                         // (B,n,256) bf16 = 67 MB

    hipMemsetAsync(w, 0, 3072, stream);   // zero BN accumulators

    k_prep_u<<<512, 256, 0, stream>>>(unknown, Aprep);
    k_prep_k<<<128, 256, 0, stream>>>(known, Bprep, kco);
    k_nn<<<dim3(N_ / 256, 2, B_), 256, 0, stream>>>(Aprep, Bprep, unknown, kco, pc);
    k_nn_merge<<<512, 256, 0, stream>>>(pc, idx);
    k_tr_kf<<<dim3(256, 4, 2), 256, 0, stream>>>(kf, kfT);
    k_tr_uf<<<dim3(1024, 2, 2), 256, 0, stream>>>(uf, newF);
    k_gather<<<dim3(8192, 2), 256, 0, stream>>>(kfT, idx, newF);
    k_gemm1<<<dim3(512, 2, 2), 256, 0, stream>>>(newF, w1, y1, bn1_sum, bn1_sq);
    k_bn_fin<<<1, 256, 0, stream>>>(bn1_sum, bn1_sq, g1, be1, s1, b1, 256, 1.f / 131072.f);
    k_gemm2<<<dim3(512, 1, 2), 256, 0, stream>>>(y1, w2, s1, b1, y2, bn2_sum, bn2_sq);
    k_bn_fin<<<1, 256, 0, stream>>>(bn2_sum, bn2_sq, g2, be2, s2, b2, 128, 1.f / 131072.f);
    k_out<<<dim3(1024, 2, 2), 256, 0, stream>>>(y2, s2, b2, out);
}

// Round 8
// 555.891 us; speedup vs baseline: 1.0664x; 1.0664x over previous
//
#include <hip/hip_runtime.h>

typedef unsigned short u16;
typedef unsigned int u32;
typedef __bf16 bf16x8 __attribute__((ext_vector_type(8)));
typedef _Float16 f16;
typedef _Float16 f16x8 __attribute__((ext_vector_type(8)));
typedef float f32x4 __attribute__((ext_vector_type(4)));
typedef float f32x16 __attribute__((ext_vector_type(16)));

#define B_ 2
#define N_ 65536
#define M_ 16384
#define C1_ 128
#define C2_ 256
#define K1_ 384   // C1+C2
#define O1_ 256   // mlp[1]
#define O2_ 128   // mlp[2]
#define JT_ 512       // 32-wide j-tiles per batch (M_/32)
// Keys scaled by S^2 = 65536 (S=256 folded into the f16 splits) — keeps every
// split residual in the f16 NORMAL range (no denormal flush). Certified
// |key/S^2 - (d-u2)| <= ~3e-4; EPS2_ = 2e-3*S^2 (>= 6x margin).
#define EPS2_ 131.072f
#define TFIN_ 8.0f    // scaled (1.2e-4 unscaled) threshold-fold inflation

__device__ __forceinline__ u16 f2bf(float f) {
    u32 u = __float_as_uint(f);
    u32 r = (u + 0x7FFFu + ((u >> 16) & 1u)) >> 16;   // RNE
    return (u16)r;
}
__device__ __forceinline__ float bf2f(u16 h) {
    return __uint_as_float(((u32)h) << 16);
}
__device__ __forceinline__ u32 pack2(float lo, float hi) {
    return (u32)f2bf(lo) | ((u32)f2bf(hi) << 16);
}
__device__ __forceinline__ uint4 pack8(float4 a, float4 b) {
    uint4 r;
    r.x = pack2(a.x, a.y); r.y = pack2(a.z, a.w);
    r.z = pack2(b.x, b.y); r.w = pack2(b.z, b.w);
    return r;
}
__device__ __forceinline__ u16 h2u(f16 h) {
    union { f16 h; u16 u; } c; c.h = h; return c.u;
}

// Exact-IEEE fp32 mul with an optimization barrier so the backend can NEVER
// contract it into an FMA (HIP default is -ffp-contract=fast).
__device__ __forceinline__ float mul_rn(float a, float b) {
    float p = __fmul_rn(a, b);
    asm volatile("" : "+v"(p));
    return p;
}
// u2/k2: elementwise-square (each product rounded) + ascending reduce
__device__ __forceinline__ float sq3_np(float x, float y, float z) {
    return __fadd_rn(__fadd_rn(mul_rn(x, x), mul_rn(y, y)), mul_rn(z, z));
}
// Eigen/XLA gebp K=3 dot: ascending k, FMA accumulate into rounded first product
__device__ __forceinline__ float dot3_fma(float a0, float b0, float a1, float b1,
                                          float a2, float b2) {
    return fmaf(a2, b2, fmaf(a1, b1, mul_rn(a0, b0)));
}

// ============================== NN search: 32x32x16 MFMA filter + exact refine
// Numerics identical to round 7 (passed, bit-exact): scaled key via
// mfma_f32_32x32x16_f16, K-slots 0-8 split coords, 9-10 k2, 11-12 pass-B
// threshold fold => MFMA emits key - thr' (thr' > thr strictly => needed
// candidates strictly negative => sign-bit OR detection is certified).
// Restructure vs r7: ONE 32-row tile/wave, FULL-M sweep (tighter threshold,
// no halves/merge, idx written directly); LDS u-row cache for refines;
// lighter live-register set (~78) to avoid the 64v+64a AGPR-shuttle split.

__global__ __launch_bounds__(256) void k_prep_u(const float* __restrict__ unk,
                                                u16* __restrict__ Aprep) {
    int g = blockIdx.x * 256 + threadIdx.x;          // over B*N
    const float* up = unk + (size_t)g * 3;
    float tx = -512.f * up[0], ty = -512.f * up[1], tz = -512.f * up[2];
    f16 xh = (f16)tx; f16 xl = (f16)(tx - (float)xh);
    f16 yh = (f16)ty; f16 yl = (f16)(ty - (float)yh);
    f16 zh = (f16)tz; f16 zl = (f16)(tz - (float)zh);
    u16 lo[8] = {h2u(xh), h2u(xh), h2u(xl), h2u(yh), h2u(yh), h2u(yl), h2u(zh), h2u(zh)};
    u16 hi[8] = {h2u(zl), 0x5C00u, 0x5C00u, 0, 0, 0, 0, 0};   // 256.0 f16
    u16* tb = Aprep + ((size_t)(g >> 5)) * 512;      // tile = 64 lanes * 8 u16
    int r = g & 31;
    *(uint4*)(tb + r * 8) = *(uint4*)lo;
    *(uint4*)(tb + (r + 32) * 8) = *(uint4*)hi;
}

__global__ __launch_bounds__(256) void k_prep_k(const float* __restrict__ kn,
                                                u16* __restrict__ Bprep,
                                                float4* __restrict__ kco) {
    int g = blockIdx.x * 256 + threadIdx.x;          // over B*M
    const float* kp = kn + (size_t)g * 3;
    float x = kp[0], y = kp[1], z = kp[2];
    float qv = sq3_np(x, y, z);                       // EXACT ref k2 sequence
    float sx = 256.f * x, sy = 256.f * y, sz = 256.f * z, sq = 256.f * qv;
    f16 xh = (f16)sx; f16 xl = (f16)(sx - (float)xh);
    f16 yh = (f16)sy; f16 yl = (f16)(sy - (float)yh);
    f16 zh = (f16)sz; f16 zl = (f16)(sz - (float)zh);
    f16 qh = (f16)sq; f16 ql = (f16)(sq - (float)qh);
    u16 lo[8] = {h2u(xh), h2u(xl), h2u(xh), h2u(yh), h2u(yl), h2u(yh), h2u(zh), h2u(zl)};
    // slots 11,12 = 256.0 so pass B's A-side -(thr)/256 split rides the MFMA
    u16 hi[8] = {h2u(zh), h2u(qh), h2u(ql), 0x5C00u, 0x5C00u, 0, 0, 0};
    u16* tb = Bprep + ((size_t)(g >> 5)) * 512;
    int r = g & 31;
    *(uint4*)(tb + r * 8) = *(uint4*)lo;
    *(uint4*)(tb + (r + 32) * 8) = *(uint4*)hi;
    kco[g] = make_float4(x, y, z, qv);
}

__global__ __launch_bounds__(256, 4) void k_nn(
        const u16* __restrict__ Aprep, const u16* __restrict__ Bprep,
        const float* __restrict__ unk, const float4* __restrict__ kco,
        int* __restrict__ idx) {
    __shared__ unsigned long long cand[128];   // wave-private 32-row slices
    __shared__ float thrS[128];
    __shared__ float4 uS[128];                 // cached (x,y,z,u2) per row
    const int t = threadIdx.x, b = blockIdx.y;
    const int lane = t & 63, w = t >> 6;
    const int rowbase = blockIdx.x * 128;            // 128 rows per block
    // wave w owns ONE 32-row tile: rows [rowbase + w*32, +32)
    const u16* at = Aprep + (((size_t)(b * N_ + rowbase + w * 32)) >> 5) * 512;
    f16x8 af = *(const f16x8*)(at + lane * 8);
    const u16* Bp = Bprep + ((size_t)b * JT_) * 512 + lane * 8;

    if (t < 128) {
        const float* up = unk + ((size_t)(b * N_ + rowbase + t)) * 3;
        float x = up[0], y = up[1], z = up[2];
        uS[t] = make_float4(x, y, z, sq3_np(x, y, z));
        cand[t] = ~0ULL;
    }
    __syncthreads();

    const f32x16 zz = {0.f,0.f,0.f,0.f,0.f,0.f,0.f,0.f,0.f,0.f,0.f,0.f,0.f,0.f,0.f,0.f};

    // ---------------- pass A: rowmin over FULL M (no barriers) --------------
    f32x16 rm;
#pragma unroll
    for (int r = 0; r < 16; ++r) rm[r] = 3.4e38f;

    // 2-tile-ahead rotation; final prefetch reads <=1 KB past this batch's
    // Bprep (next batch / kco region -- mapped workspace, values unused).
    f16x8 c0 = *(const f16x8*)Bp;
    f16x8 c1 = *(const f16x8*)(Bp + 512);
    for (int tp = 0; tp < JT_; tp += 2) {
        f16x8 n0 = *(const f16x8*)(Bp + 1024);
        f16x8 n1 = *(const f16x8*)(Bp + 1536);
        Bp += 1024;
        f32x16 a  = __builtin_amdgcn_mfma_f32_32x32x16_f16(af, c0, zz, 0, 0, 0);
        f32x16 ca = __builtin_amdgcn_mfma_f32_32x32x16_f16(af, c1, zz, 0, 0, 0);
#pragma unroll
        for (int r = 0; r < 16; ++r)
            rm[r] = fminf(fminf(rm[r], a[r]), ca[r]);
        c0 = n0; c1 = n1;
    }

    // reduce over the 32 cols -> per-row thresholds (wave-private LDS slice)
#pragma unroll
    for (int r = 0; r < 16; ++r) {
        float v = rm[r];
        v = fminf(v, __shfl_xor(v, 1));
        v = fminf(v, __shfl_xor(v, 2));
        v = fminf(v, __shfl_xor(v, 4));
        v = fminf(v, __shfl_xor(v, 8));
        v = fminf(v, __shfl_xor(v, 16));
        if ((lane & 31) == 0) {
            int rl = w * 32 + ((lane >> 5) << 2) + (r & 3) + 8 * (r >> 2);
            thrS[rl] = v + EPS2_;
        }
    }
    // patch A fragment: k-slots 11,12 (lanes>=32, elems 3,4) =
    // split(-(thr+TFIN_)/256); product with B slots (=256) gives -(thr+TFIN_)
    // (same-wave LDS RAW -> compiler lgkmcnt; no barrier needed)
    if (lane >= 32) {
        float tf = (thrS[w * 32 + (lane & 31)] + TFIN_) * 0.00390625f;
        f16 h0 = (f16)(-tf);
        af[3] = h0; af[4] = (f16)(-tf - (float)h0);
    }

    // ---------------- pass B: exact refine (MFMA emits key - thr') ----------
    const float4* kcb = kco + (size_t)b * M_;
    const int rloc0 = w * 32 + ((lane >> 5) << 2);   // + rr + 8*g

#define REFINE(RL, AV)                                                         \
    if ((AV) <= 0.f) {                                                         \
        int rl = (RL);                                                         \
        float4 uv = uS[rl];                                                    \
        float dot = dot3_fma(uv.x, kc.x, uv.y, kc.y, uv.z, kc.z);              \
        float d = __fadd_rn(fmaf(-2.0f, dot, uv.w), kc.w);                     \
        u32 db = __float_as_uint(d);                                           \
        db = (db & 0x80000000u) ? ~db : (db | 0x80000000u);                    \
        atomicMin(&cand[rl], ((unsigned long long)db << 32) | (u32)j);         \
    }

    Bp -= (size_t)JT_ * 512;                         // rewind to batch start
    c0 = *(const f16x8*)Bp;
    f16x8 c1b = *(const f16x8*)(Bp + 512);
    for (int tt = 0; tt < JT_; ++tt) {
        f16x8 nx = *(const f16x8*)(Bp + 1024);
        Bp += 512;
        f32x16 a = __builtin_amdgcn_mfma_f32_32x32x16_f16(af, c0, zz, 0, 0, 0);
        // sign-bit OR detection: candidate iff key - thr' < 0 (certified
        // strict for all needed candidates; refine gate <=0 is a superset)
        u32 g0 = __float_as_uint(a[0]) | __float_as_uint(a[1])
               | __float_as_uint(a[2]) | __float_as_uint(a[3]);
        u32 g1 = __float_as_uint(a[4]) | __float_as_uint(a[5])
               | __float_as_uint(a[6]) | __float_as_uint(a[7]);
        u32 g2 = __float_as_uint(a[8]) | __float_as_uint(a[9])
               | __float_as_uint(a[10]) | __float_as_uint(a[11]);
        u32 g3 = __float_as_uint(a[12]) | __float_as_uint(a[13])
               | __float_as_uint(a[14]) | __float_as_uint(a[15]);
        u32 oall = g0 | g1 | g2 | g3;
        if (__ballot((int)oall < 0)) {               // rarely taken
            int j = tt * 32 + (lane & 31);
            float4 kc = kcb[j];
            if (__any((int)g0 < 0)) {
#pragma unroll
                for (int rr = 0; rr < 4; ++rr) REFINE(rloc0 + rr, a[rr])
            }
            if (__any((int)g1 < 0)) {
#pragma unroll
                for (int rr = 0; rr < 4; ++rr) REFINE(rloc0 + 8 + rr, a[4 + rr])
            }
            if (__any((int)g2 < 0)) {
#pragma unroll
                for (int rr = 0; rr < 4; ++rr) REFINE(rloc0 + 16 + rr, a[8 + rr])
            }
            if (__any((int)g3 < 0)) {
#pragma unroll
                for (int rr = 0; rr < 4; ++rr) REFINE(rloc0 + 24 + rr, a[12 + rr])
            }
        }
        c0 = c1b; c1b = nx;
    }
#undef REFINE
    __syncthreads();
    if (t < 128)
        idx[b * N_ + rowbase + t] = (int)(u32)(cand[t] & 0xFFFFFFFFu);
}

// ------------------------------------------- transpose known_feats -> (b,m,c) bf16
__global__ __launch_bounds__(256) void k_tr_kf(const float* __restrict__ kf,
                                               u16* __restrict__ kfT) {
    __shared__ float lt[64][65];
    const int t = threadIdx.x, b = blockIdx.z;
    const int j0 = blockIdx.x * 64, c0 = blockIdx.y * 64;
    const int jl = t & 63, cl4 = t >> 6;
#pragma unroll
    for (int p = 0; p < 16; ++p) {
        int c = c0 + cl4 + p * 4;
        lt[cl4 + p * 4][jl] = kf[((size_t)(b * C2_ + c)) * M_ + j0 + jl];
    }
    __syncthreads();
    const int cl = t & 63, jr4 = t >> 6;
#pragma unroll
    for (int p = 0; p < 16; ++p) {
        int j = j0 + jr4 + p * 4;
        kfT[((size_t)(b * M_ + j)) * C2_ + c0 + cl] = f2bf(lt[cl][jr4 + p * 4]);
    }
}

// --------------------------- transpose unknow_feats -> dense ufT (b,n,128) bf16
__global__ __launch_bounds__(256) void k_tr_uf(const float* __restrict__ uf,
                                               u16* __restrict__ ufT) {
    __shared__ float lt[64][65];
    const int t = threadIdx.x, b = blockIdx.z;
    const int i0 = blockIdx.x * 64, c0 = blockIdx.y * 64;
    const int il = t & 63, cl4 = t >> 6;
#pragma unroll
    for (int p = 0; p < 16; ++p) {
        int c = c0 + cl4 + p * 4;
        lt[cl4 + p * 4][il] = uf[((size_t)(b * C1_ + c)) * N_ + i0 + il];
    }
    __syncthreads();
    const int cl = t & 63, ir4 = t >> 6;
#pragma unroll
    for (int p = 0; p < 16; ++p) {
        int i = i0 + ir4 + p * 4;
        ufT[((size_t)(b * N_ + i)) * C1_ + c0 + cl] = f2bf(lt[cl][ir4 + p * 4]);
    }
}

// ---------------------------------------------------------------- GEMM1
// y1[b][i][o] (bf16) = [kfT[idx[i]][0:256] ++ ufT[i][0:128]] . w1[o][:]
// (gather fused into A-staging). BN1 stats fused in epilogue.
__global__ __launch_bounds__(256) void k_gemm1(const u16* __restrict__ kfT,
                                               const u16* __restrict__ ufT,
                                               const int* __restrict__ idx,
                                               const float* __restrict__ w1,
                                               u16* __restrict__ y1,
                                               float* __restrict__ bsum,
                                               float* __restrict__ bsq) {
    __shared__ u16 As[128 * 40];
    __shared__ u16 Bs[128 * 40];
    const int t = threadIdx.x, b = blockIdx.z;
    const int i0 = blockIdx.x * 128, o0 = blockIdx.y * 128;
    const int lane = t & 63, wv = t >> 6, wr = wv >> 1, wc = wv & 1;
    const int col = lane & 15, q = lane >> 4;

    const int rA0 = t >> 2, sA0 = t & 3;   // +256 => row+64, same sub
    const int j0 = idx[b * N_ + i0 + rA0];
    const int j1 = idx[b * N_ + i0 + 64 + rA0];
    const u16* kA0 = kfT + ((size_t)(b * M_ + j0)) * C2_ + sA0 * 8;
    const u16* kA1 = kfT + ((size_t)(b * M_ + j1)) * C2_ + sA0 * 8;
    const u16* uA0 = ufT + ((size_t)(b * N_ + i0 + rA0)) * C1_ + sA0 * 8;
    const u16* uA1 = uA0 + (size_t)64 * C1_;
    const float* bS0 = w1 + (size_t)(o0 + rA0) * K1_ + sA0 * 8;
    const float* bS1 = bS0 + (size_t)64 * K1_;
    u16* aD0 = &As[rA0 * 40 + sA0 * 8];
    u16* aD1 = aD0 + 64 * 40;
    u16* bD0 = &Bs[rA0 * 40 + sA0 * 8];
    u16* bD1 = bD0 + 64 * 40;

    f32x4 acc[4][4];
#pragma unroll
    for (int m = 0; m < 4; ++m)
#pragma unroll
        for (int n = 0; n < 4; ++n) acc[m][n] = (f32x4){0.f, 0.f, 0.f, 0.f};

    uint4 a0 = *(const uint4*)kA0, a1 = *(const uint4*)kA1;
    float4 f00 = *(const float4*)bS0, f01 = *(const float4*)(bS0 + 4);
    float4 f10 = *(const float4*)bS1, f11 = *(const float4*)(bS1 + 4);

    for (int ks = 0; ks < 12; ++ks) {
        __syncthreads();
        *(uint4*)aD0 = a0; *(uint4*)aD1 = a1;
        *(uint4*)bD0 = pack8(f00, f01); *(uint4*)bD1 = pack8(f10, f11);
        __syncthreads();
        if (ks < 11) {
            int kn = ks + 1;
            if (kn < 8) {                 // cols 0..255 from gathered kfT rows
                a0 = *(const uint4*)(kA0 + kn * 32);
                a1 = *(const uint4*)(kA1 + kn * 32);
            } else {                      // cols 256..383 from ufT
                a0 = *(const uint4*)(uA0 + (kn - 8) * 32);
                a1 = *(const uint4*)(uA1 + (kn - 8) * 32);
            }
            int ko = kn * 32;
            f00 = *(const float4*)(bS0 + ko); f01 = *(const float4*)(bS0 + ko + 4);
            f10 = *(const float4*)(bS1 + ko); f11 = *(const float4*)(bS1 + ko + 4);
        }
        const u16* ap = &As[(wr * 64 + col) * 40 + q * 8];
        const u16* bp = &Bs[(wc * 64 + col) * 40 + q * 8];
        bf16x8 af[4], bfr[4];
#pragma unroll
        for (int m = 0; m < 4; ++m) af[m] = *(const bf16x8*)(ap + m * 640);
#pragma unroll
        for (int n = 0; n < 4; ++n) bfr[n] = *(const bf16x8*)(bp + n * 640);
#pragma unroll
        for (int m = 0; m < 4; ++m)
#pragma unroll
            for (int n = 0; n < 4; ++n)
                acc[m][n] = __builtin_amdgcn_mfma_f32_16x16x32_bf16(af[m], bfr[n], acc[m][n], 0, 0, 0);
    }
    float ssum[4], ssq[4];
#pragma unroll
    for (int n = 0; n < 4; ++n) { ssum[n] = 0.f; ssq[n] = 0.f; }
#pragma unroll
    for (int m = 0; m < 4; ++m)
#pragma unroll
        for (int n = 0; n < 4; ++n) {
            int go = o0 + wc * 64 + n * 16 + col;
#pragma unroll
            for (int r = 0; r < 4; ++r) {
                int gi = i0 + wr * 64 + m * 16 + q * 4 + r;
                u16 hv = f2bf(acc[m][n][r]);
                y1[((size_t)(b * N_ + gi)) * O1_ + go] = hv;
                float v = bf2f(hv);
                ssum[n] += v; ssq[n] = fmaf(v, v, ssq[n]);
            }
        }
#pragma unroll
    for (int n = 0; n < 4; ++n) {
        float s = ssum[n], qv = ssq[n];
        s += __shfl_xor(s, 16); qv += __shfl_xor(qv, 16);
        s += __shfl_xor(s, 32); qv += __shfl_xor(qv, 32);
        if (q == 0) {
            int go = o0 + wc * 64 + n * 16 + col;
            atomicAdd(&bsum[go], s);
            atomicAdd(&bsq[go], qv);
        }
    }
}

__global__ void k_bn_fin(const float* __restrict__ sum, const float* __restrict__ sq,
                         const float* __restrict__ gamma, const float* __restrict__ beta,
                         float* __restrict__ scale, float* __restrict__ bias,
                         int C, float invN) {
    int t = threadIdx.x;
    if (t < C) {
        float mean = sum[t] * invN;
        float var = sq[t] * invN - mean * mean;
        float rs = rsqrtf(var + 1e-5f);
        float sc = gamma[t] * rs;
        scale[t] = sc;
        bias[t] = beta[t] - mean * sc;
    }
}

// ---------------------------------------------------------------- GEMM2
// y2[b][i][o] (f32) = relu(bn1(y1))[b][i][:] . w2[o][:]  (BN1 fused in A-staging)
// BN2 stats fused in epilogue (on the raw f32 values)
__global__ __launch_bounds__(256) void k_gemm2(const u16* __restrict__ y1,
                                               const float* __restrict__ w2,
                                               const float* __restrict__ s1,
                                               const float* __restrict__ b1,
                                               float* __restrict__ y2,
                                               float* __restrict__ bsum,
                                               float* __restrict__ bsq) {
    __shared__ u16 As[128 * 40];
    __shared__ u16 Bs[128 * 40];
    const int t = threadIdx.x, b = blockIdx.z;
    const int i0 = blockIdx.x * 128;
    const int lane = t & 63, wv = t >> 6, wr = wv >> 1, wc = wv & 1;
    const int col = lane & 15, q = lane >> 4;

    const int rA0 = t >> 2, sA0 = t & 3;
    const u16* aS0 = y1 + ((size_t)(b * N_ + i0 + rA0)) * O1_ + sA0 * 8;
    const u16* aS1 = aS0 + (size_t)64 * O1_;
    const float* bS0 = w2 + (size_t)rA0 * O1_ + sA0 * 8;
    const float* bS1 = bS0 + (size_t)64 * O1_;
    u16* aD0 = &As[rA0 * 40 + sA0 * 8];
    u16* aD1 = aD0 + 64 * 40;
    u16* bD0 = &Bs[rA0 * 40 + sA0 * 8];
    u16* bD1 = bD0 + 64 * 40;

    f32x4 acc[4][4];
#pragma unroll
    for (int m = 0; m < 4; ++m)
#pragma unroll
        for (int n = 0; n < 4; ++n) acc[m][n] = (f32x4){0.f, 0.f, 0.f, 0.f};

    uint4 a0 = *(const uint4*)aS0, a1 = *(const uint4*)aS1;
    float4 f00 = *(const float4*)bS0, f01 = *(const float4*)(bS0 + 4);
    float4 f10 = *(const float4*)bS1, f11 = *(const float4*)(bS1 + 4);

    for (int ks = 0; ks < 8; ++ks) {
        int oc = ks * 32 + sA0 * 8;
        float4 sc0 = *(const float4*)(s1 + oc), sc1 = *(const float4*)(s1 + oc + 4);
        float4 bb0 = *(const float4*)(b1 + oc), bb1 = *(const float4*)(b1 + oc + 4);
        uint4 h0, h1;
        {
            const u16* hs = (const u16*)&a0;
            float v[8];
            v[0] = fmaxf(fmaf(bf2f(hs[0]), sc0.x, bb0.x), 0.f);
            v[1] = fmaxf(fmaf(bf2f(hs[1]), sc0.y, bb0.y), 0.f);
            v[2] = fmaxf(fmaf(bf2f(hs[2]), sc0.z, bb0.z), 0.f);
            v[3] = fmaxf(fmaf(bf2f(hs[3]), sc0.w, bb0.w), 0.f);
            v[4] = fmaxf(fmaf(bf2f(hs[4]), sc1.x, bb1.x), 0.f);
            v[5] = fmaxf(fmaf(bf2f(hs[5]), sc1.y, bb1.y), 0.f);
            v[6] = fmaxf(fmaf(bf2f(hs[6]), sc1.z, bb1.z), 0.f);
            v[7] = fmaxf(fmaf(bf2f(hs[7]), sc1.w, bb1.w), 0.f);
            h0.x = pack2(v[0], v[1]); h0.y = pack2(v[2], v[3]);
            h0.z = pack2(v[4], v[5]); h0.w = pack2(v[6], v[7]);
        }
        {
            const u16* hs = (const u16*)&a1;
            float v[8];
            v[0] = fmaxf(fmaf(bf2f(hs[0]), sc0.x, bb0.x), 0.f);
            v[1] = fmaxf(fmaf(bf2f(hs[1]), sc0.y, bb0.y), 0.f);
            v[2] = fmaxf(fmaf(bf2f(hs[2]), sc0.z, bb0.z), 0.f);
            v[3] = fmaxf(fmaf(bf2f(hs[3]), sc0.w, bb0.w), 0.f);
            v[4] = fmaxf(fmaf(bf2f(hs[4]), sc1.x, bb1.x), 0.f);
            v[5] = fmaxf(fmaf(bf2f(hs[5]), sc1.y, bb1.y), 0.f);
            v[6] = fmaxf(fmaf(bf2f(hs[6]), sc1.z, bb1.z), 0.f);
            v[7] = fmaxf(fmaf(bf2f(hs[7]), sc1.w, bb1.w), 0.f);
            h1.x = pack2(v[0], v[1]); h1.y = pack2(v[2], v[3]);
            h1.z = pack2(v[4], v[5]); h1.w = pack2(v[6], v[7]);
        }
        __syncthreads();
        *(uint4*)aD0 = h0; *(uint4*)aD1 = h1;
        *(uint4*)bD0 = pack8(f00, f01); *(uint4*)bD1 = pack8(f10, f11);
        __syncthreads();
        if (ks < 7) {
            int ko = (ks + 1) * 32;
            a0 = *(const uint4*)(aS0 + ko); a1 = *(const uint4*)(aS1 + ko);
            f00 = *(const float4*)(bS0 + ko); f01 = *(const float4*)(bS0 + ko + 4);
            f10 = *(const float4*)(bS1 + ko); f11 = *(const float4*)(bS1 + ko + 4);
        }
        const u16* ap = &As[(wr * 64 + col) * 40 + q * 8];
        const u16* bp = &Bs[(wc * 64 + col) * 40 + q * 8];
        bf16x8 af[4], bfr[4];
#pragma unroll
        for (int m = 0; m < 4; ++m) af[m] = *(const bf16x8*)(ap + m * 640);
#pragma unroll
        for (int n = 0; n < 4; ++n) bfr[n] = *(const bf16x8*)(bp + n * 640);
#pragma unroll
        for (int m = 0; m < 4; ++m)
#pragma unroll
            for (int n = 0; n < 4; ++n)
                acc[m][n] = __builtin_amdgcn_mfma_f32_16x16x32_bf16(af[m], bfr[n], acc[m][n], 0, 0, 0);
    }
    float ssum[4], ssq[4];
#pragma unroll
    for (int n = 0; n < 4; ++n) { ssum[n] = 0.f; ssq[n] = 0.f; }
#pragma unroll
    for (int m = 0; m < 4; ++m)
#pragma unroll
        for (int n = 0; n < 4; ++n) {
            int go = wc * 64 + n * 16 + col;
#pragma unroll
            for (int r = 0; r < 4; ++r) {
                int gi = i0 + wr * 64 + m * 16 + q * 4 + r;
                float v = acc[m][n][r];
                y2[((size_t)(b * N_ + gi)) * O2_ + go] = v;
                ssum[n] += v; ssq[n] = fmaf(v, v, ssq[n]);
            }
        }
#pragma unroll
    for (int n = 0; n < 4; ++n) {
        float s = ssum[n], qv = ssq[n];
        s += __shfl_xor(s, 16); qv += __shfl_xor(qv, 16);
        s += __shfl_xor(s, 32); qv += __shfl_xor(qv, 32);
        if (q == 0) {
            int go = wc * 64 + n * 16 + col;
            atomicAdd(&bsum[go], s);
            atomicAdd(&bsq[go], qv);
        }
    }
}

// ---------------------------- BN2 affine + ReLU + transpose (b,i,o)->(b,o,i) out
__global__ __launch_bounds__(256) void k_out(const float* __restrict__ y2,
                                             const float* __restrict__ s2,
                                             const float* __restrict__ b2,
                                             float* __restrict__ out) {
    __shared__ float lt[64 * 65];
    const int t = threadIdx.x, b = blockIdx.z;
    const int i0 = blockIdx.x * 64, o0 = blockIdx.y * 64;
    const int oc = t & 63, ir4 = t >> 6;
    const float sc = s2[o0 + oc], bs = b2[o0 + oc];
#pragma unroll
    for (int p = 0; p < 16; ++p) {
        int i = i0 + ir4 + p * 4;
        float v = y2[((size_t)(b * N_ + i)) * O2_ + o0 + oc];
        lt[oc * 65 + ir4 + p * 4] = fmaxf(fmaf(v, sc, bs), 0.f);
    }
    __syncthreads();
    const int il = t & 63, or4 = t >> 6;
#pragma unroll
    for (int p = 0; p < 16; ++p) {
        int o = o0 + or4 + p * 4;
        out[((size_t)(b * O2_ + o)) * N_ + i0 + il] = lt[(or4 + p * 4) * 65 + il];
    }
}

extern "C" void kernel_launch(void* const* d_in, const int* in_sizes, int n_in,
                              void* d_out, int out_size, void* d_ws, size_t ws_size,
                              hipStream_t stream) {
    const float* unknown = (const float*)d_in[0];
    const float* known   = (const float*)d_in[1];
    const float* uf      = (const float*)d_in[2];
    const float* kf      = (const float*)d_in[3];
    const float* w1      = (const float*)d_in[4];
    const float* g1      = (const float*)d_in[5];
    const float* be1     = (const float*)d_in[6];
    const float* w2      = (const float*)d_in[7];
    const float* g2      = (const float*)d_in[8];
    const float* be2     = (const float*)d_in[9];
    float* out = (float*)d_out;

    char* w = (char*)d_ws;
    // stats block (zeroed each call): bn1_sum[256] bn1_sq[256] bn2_sum[128] bn2_sq[128]
    float* bn1_sum = (float*)w;
    float* bn1_sq  = bn1_sum + 256;
    float* bn2_sum = bn1_sq + 256;
    float* bn2_sq  = bn2_sum + 128;
    float* s1 = (float*)(w + 4096);     // 256
    float* b1 = s1 + 256;               // 256
    float* s2 = b1 + 256;               // 128
    float* b2 = s2 + 128;               // 128
    int* idx = (int*)(w + 8192);                        // 512 KiB -> ends 532480
    u16* ufT = (u16*)(w + 532480);                      // (B,n,128) bf16 = 33.5 MB
    size_t A1 = 532480 + 33554432ULL;
    u16* y1  = (u16*)(w + A1);                          // (B,n,256) bf16 = 67 MB
    size_t A2 = A1 + 67108864ULL;
    u16* kfT = (u16*)(w + A2);                          // (B,m,256) bf16 = 16.7 MB
    size_t A3 = A2 + 16777216ULL;
    u16* Aprep = (u16*)(w + A3);                        // 4 MiB
    u16* Bprep = (u16*)(w + A3 + 4194304ULL);           // 1 MiB
    float4* kco = (float4*)(w + A3 + 5242880ULL);       // 512 KiB
    size_t A4 = A3 + 5767168ULL;
    float* y2 = (float*)(w + A4);                       // (B,n,128) f32 = 67 MB

    hipMemsetAsync(w, 0, 3072, stream);   // zero BN accumulators

    k_prep_u<<<512, 256, 0, stream>>>(unknown, Aprep);
    k_prep_k<<<128, 256, 0, stream>>>(known, Bprep, kco);
    k_nn<<<dim3(N_ / 128, B_), 256, 0, stream>>>(Aprep, Bprep, unknown, kco, idx);
    k_tr_kf<<<dim3(256, 4, 2), 256, 0, stream>>>(kf, kfT);
    k_tr_uf<<<dim3(1024, 2, 2), 256, 0, stream>>>(uf, ufT);
    k_gemm1<<<dim3(512, 2, 2), 256, 0, stream>>>(kfT, ufT, idx, w1, y1, bn1_sum, bn1_sq);
    k_bn_fin<<<1, 256, 0, stream>>>(bn1_sum, bn1_sq, g1, be1, s1, b1, 256, 1.f / 131072.f);
    k_gemm2<<<dim3(512, 1, 2), 256, 0, stream>>>(y1, w2, s1, b1, y2, bn2_sum, bn2_sq);
    k_bn_fin<<<1, 256, 0, stream>>>(bn2_sum, bn2_sq, g2, be2, s2, b2, 128, 1.f / 131072.f);
    k_out<<<dim3(1024, 2, 2), 256, 0, stream>>>(y2, s2, b2, out);
}

// Round 10
// 529.120 us; speedup vs baseline: 1.1203x; 1.0506x over previous
//
#include <hip/hip_runtime.h>

typedef unsigned short u16;
typedef unsigned int u32;
typedef __bf16 bf16x8 __attribute__((ext_vector_type(8)));
typedef _Float16 f16;
typedef _Float16 f16x8 __attribute__((ext_vector_type(8)));
typedef float f32x4 __attribute__((ext_vector_type(4)));
typedef float f32x16 __attribute__((ext_vector_type(16)));

#define B_ 2
#define N_ 65536
#define M_ 16384
#define C1_ 128
#define C2_ 256
#define K1_ 384   // C1+C2
#define O1_ 256   // mlp[1]
#define O2_ 128   // mlp[2]
#define JT_ 512       // 32-wide j-tiles per batch (M_/32)
#define SUBT_ 128     // prefix tiles for the threshold (4096 points)
// Keys scaled by S^2 = 65536 (S=256 folded into the f16 splits) — keeps every
// split residual in the f16 NORMAL range (no denormal flush). Certified
// |key/S^2 - (d-u2)| <= ~3e-4; EPS2_ = 2e-3*S^2 (>= 6x margin).
// Threshold = rowmin over the PREFIX subset + EPS2_: an UPPER bound on the
// full rowmin + EPS2_ => candidate SUPERSET of the certified set => the exact
// reference-rounded refine still reproduces the reference argmin bit-exactly.
#define EPS2_ 131.072f
#define TFIN_ 8.0f    // scaled threshold-fold inflation (>= worst-case ~4)

__device__ __forceinline__ u16 f2bf(float f) {
    u32 u = __float_as_uint(f);
    u32 r = (u + 0x7FFFu + ((u >> 16) & 1u)) >> 16;   // RNE
    return (u16)r;
}
__device__ __forceinline__ float bf2f(u16 h) {
    return __uint_as_float(((u32)h) << 16);
}
__device__ __forceinline__ u32 pack2(float lo, float hi) {
    return (u32)f2bf(lo) | ((u32)f2bf(hi) << 16);
}
__device__ __forceinline__ uint4 pack8(float4 a, float4 b) {
    uint4 r;
    r.x = pack2(a.x, a.y); r.y = pack2(a.z, a.w);
    r.z = pack2(b.x, b.y); r.w = pack2(b.z, b.w);
    return r;
}
__device__ __forceinline__ u16 h2u(f16 h) {
    union { f16 h; u16 u; } c; c.h = h; return c.u;
}

// Exact-IEEE fp32 mul with an optimization barrier so the backend can NEVER
// contract it into an FMA (HIP default is -ffp-contract=fast).
__device__ __forceinline__ float mul_rn(float a, float b) {
    float p = __fmul_rn(a, b);
    asm volatile("" : "+v"(p));
    return p;
}
// u2/k2: elementwise-square (each product rounded) + ascending reduce
__device__ __forceinline__ float sq3_np(float x, float y, float z) {
    return __fadd_rn(__fadd_rn(mul_rn(x, x), mul_rn(y, y)), mul_rn(z, z));
}
// Eigen/XLA gebp K=3 dot: ascending k, FMA accumulate into rounded first product
__device__ __forceinline__ float dot3_fma(float a0, float b0, float a1, float b1,
                                          float a2, float b2) {
    return fmaf(a2, b2, fmaf(a1, b1, mul_rn(a0, b0)));
}

// ============================== NN search: 32x32x16 MFMA filter + exact refine
// Numerics == rounds 7/8 (both passed, bit-exact). BUILTIN MFMAs only (the r9
// inline-asm variant violated a hazard and mis-indexed; reverted). Changes vs
// r8: (1) pass A over only SUBT_ prefix tiles (threshold upper bound —
// certified superset); (2) detection = one or3 sign-tree + single ballot,
// group masks only inside the taken branch; (3) LDS u-row cache for refines;
// (4) idx written directly (no halves/merge).

__global__ __launch_bounds__(256) void k_prep_u(const float* __restrict__ unk,
                                                u16* __restrict__ Aprep) {
    int g = blockIdx.x * 256 + threadIdx.x;          // over B*N
    const float* up = unk + (size_t)g * 3;
    float tx = -512.f * up[0], ty = -512.f * up[1], tz = -512.f * up[2];
    f16 xh = (f16)tx; f16 xl = (f16)(tx - (float)xh);
    f16 yh = (f16)ty; f16 yl = (f16)(ty - (float)yh);
    f16 zh = (f16)tz; f16 zl = (f16)(tz - (float)zh);
    u16 lo[8] = {h2u(xh), h2u(xh), h2u(xl), h2u(yh), h2u(yh), h2u(yl), h2u(zh), h2u(zh)};
    u16 hi[8] = {h2u(zl), 0x5C00u, 0x5C00u, 0, 0, 0, 0, 0};   // 256.0 f16
    u16* tb = Aprep + ((size_t)(g >> 5)) * 512;      // tile = 64 lanes * 8 u16
    int r = g & 31;
    *(uint4*)(tb + r * 8) = *(uint4*)lo;
    *(uint4*)(tb + (r + 32) * 8) = *(uint4*)hi;
}

__global__ __launch_bounds__(256) void k_prep_k(const float* __restrict__ kn,
                                                u16* __restrict__ Bprep,
                                                float4* __restrict__ kco) {
    int g = blockIdx.x * 256 + threadIdx.x;          // over B*M
    const float* kp = kn + (size_t)g * 3;
    float x = kp[0], y = kp[1], z = kp[2];
    float qv = sq3_np(x, y, z);                       // EXACT ref k2 sequence
    float sx = 256.f * x, sy = 256.f * y, sz = 256.f * z, sq = 256.f * qv;
    f16 xh = (f16)sx; f16 xl = (f16)(sx - (float)xh);
    f16 yh = (f16)sy; f16 yl = (f16)(sy - (float)yh);
    f16 zh = (f16)sz; f16 zl = (f16)(sz - (float)zh);
    f16 qh = (f16)sq; f16 ql = (f16)(sq - (float)qh);
    u16 lo[8] = {h2u(xh), h2u(xl), h2u(xh), h2u(yh), h2u(yl), h2u(yh), h2u(zh), h2u(zl)};
    // slots 11,12 = 256.0 so the A-side -(thr)/256 split rides the MFMA
    u16 hi[8] = {h2u(zh), h2u(qh), h2u(ql), 0x5C00u, 0x5C00u, 0, 0, 0};
    u16* tb = Bprep + ((size_t)(g >> 5)) * 512;
    int r = g & 31;
    *(uint4*)(tb + r * 8) = *(uint4*)lo;
    *(uint4*)(tb + (r + 32) * 8) = *(uint4*)hi;
    kco[g] = make_float4(x, y, z, qv);
}

__global__ __launch_bounds__(256, 4) void k_nn(
        const u16* __restrict__ Aprep, const u16* __restrict__ Bprep,
        const float* __restrict__ unk, const float4* __restrict__ kco,
        int* __restrict__ idx) {
    __shared__ unsigned long long cand[128];   // wave-private 32-row slices
    __shared__ float thrS[128];
    __shared__ float4 uS[128];                 // cached (x,y,z,u2) per row
    const int t = threadIdx.x, b = blockIdx.y;
    const int lane = t & 63, w = t >> 6;
    const int rowbase = blockIdx.x * 128;            // 128 rows per block
    // wave w owns ONE 32-row tile: rows [rowbase + w*32, +32)
    const u16* at = Aprep + (((size_t)(b * N_ + rowbase + w * 32)) >> 5) * 512;
    f16x8 af = *(const f16x8*)(at + lane * 8);
    const u16* Bb = Bprep + ((size_t)b * JT_) * 512;

    if (t < 128) {
        const float* up = unk + ((size_t)(b * N_ + rowbase + t)) * 3;
        float x = up[0], y = up[1], z = up[2];
        uS[t] = make_float4(x, y, z, sq3_np(x, y, z));
        cand[t] = ~0ULL;
    }
    __syncthreads();

    const f32x16 zz = {0.f,0.f,0.f,0.f,0.f,0.f,0.f,0.f,0.f,0.f,0.f,0.f,0.f,0.f,0.f,0.f};

    // ---- pass A: rowmin over the first SUBT_ tiles (threshold upper bound) --
    {
        f32x16 rm;
#pragma unroll
        for (int r = 0; r < 16; ++r) rm[r] = 3.4e38f;
        const u16* Bp = Bb + lane * 8;
        f16x8 c0 = *(const f16x8*)Bp;
        f16x8 c1 = *(const f16x8*)(Bp + 512);
        for (int tp = 0; tp < SUBT_; tp += 2) {
            f16x8 n0 = *(const f16x8*)(Bp + 1024);
            f16x8 n1 = *(const f16x8*)(Bp + 1536);
            Bp += 1024;
            f32x16 a  = __builtin_amdgcn_mfma_f32_32x32x16_f16(af, c0, zz, 0, 0, 0);
            f32x16 ca = __builtin_amdgcn_mfma_f32_32x32x16_f16(af, c1, zz, 0, 0, 0);
#pragma unroll
            for (int r = 0; r < 16; ++r)
                rm[r] = fminf(fminf(rm[r], a[r]), ca[r]);
            c0 = n0; c1 = n1;
        }
        // reduce over the 32 cols -> per-row thresholds (wave-private slice)
#pragma unroll
        for (int r = 0; r < 16; ++r) {
            float v = rm[r];
            v = fminf(v, __shfl_xor(v, 1));
            v = fminf(v, __shfl_xor(v, 2));
            v = fminf(v, __shfl_xor(v, 4));
            v = fminf(v, __shfl_xor(v, 8));
            v = fminf(v, __shfl_xor(v, 16));
            if ((lane & 31) == 0) {
                int rl = w * 32 + ((lane >> 5) << 2) + (r & 3) + 8 * (r >> 2);
                thrS[rl] = v + EPS2_;
            }
        }
    }
    // patch A fragment: k-slots 11,12 (lanes>=32, elems 3,4) =
    // split(-(thr+TFIN_)/256); product with B slots (=256) gives -(thr+TFIN_)
    // (same-wave LDS RAW -> compiler-inserted lgkmcnt; no barrier needed)
    if (lane >= 32) {
        float tf = (thrS[w * 32 + (lane & 31)] + TFIN_) * 0.00390625f;
        f16 h0 = (f16)(-tf);
        af[3] = h0; af[4] = (f16)(-tf - (float)h0);
    }

    // ---- pass B: full-M sweep (MFMA emits key - thr'), exact refine --------
    const float4* kcb = kco + (size_t)b * M_;
    const int rloc0 = w * 32 + ((lane >> 5) << 2);   // + rr + 8*g

#define FU(X) __float_as_uint(X)
#define REFINE(RL, AV)                                                         \
    if ((AV) <= 0.f) {                                                         \
        int rl = (RL);                                                         \
        float4 uv = uS[rl];                                                    \
        float dot = dot3_fma(uv.x, kc.x, uv.y, kc.y, uv.z, kc.z);              \
        float d = __fadd_rn(fmaf(-2.0f, dot, uv.w), kc.w);                     \
        u32 db = __float_as_uint(d);                                           \
        db = (db & 0x80000000u) ? ~db : (db | 0x80000000u);                    \
        atomicMin(&cand[rl], ((unsigned long long)db << 32) | (u32)j);         \
    }

    {
        const u16* Bp = Bb + lane * 8;
        f16x8 c0 = *(const f16x8*)Bp;
        f16x8 c1 = *(const f16x8*)(Bp + 512);
        for (int tt = 0; tt < JT_; ++tt) {
            f16x8 nx = *(const f16x8*)(Bp + 1024);
            Bp += 512;
            f32x16 a = __builtin_amdgcn_mfma_f32_32x32x16_f16(af, c0, zz, 0, 0, 0);
            // single or3 sign-tree + one ballot; group work only when taken
            u32 oall = (FU(a[0]) | FU(a[1]) | FU(a[2]))
                     | (FU(a[3]) | FU(a[4]) | FU(a[5]))
                     | (FU(a[6]) | FU(a[7]) | FU(a[8]))
                     | (FU(a[9]) | FU(a[10]) | FU(a[11]))
                     | (FU(a[12]) | FU(a[13]) | FU(a[14]))
                     | FU(a[15]);
            if (__ballot((int)oall < 0)) {           // ~30% of tiles
                int j = tt * 32 + (lane & 31);
                float4 kc = kcb[j];
                u32 g0 = FU(a[0]) | FU(a[1]) | FU(a[2]) | FU(a[3]);
                u32 g1 = FU(a[4]) | FU(a[5]) | FU(a[6]) | FU(a[7]);
                u32 g2 = FU(a[8]) | FU(a[9]) | FU(a[10]) | FU(a[11]);
                u32 g3 = FU(a[12]) | FU(a[13]) | FU(a[14]) | FU(a[15]);
                if (__any((int)g0 < 0)) {
                    REFINE(rloc0 + 0, a[0]) REFINE(rloc0 + 1, a[1])
                    REFINE(rloc0 + 2, a[2]) REFINE(rloc0 + 3, a[3])
                }
                if (__any((int)g1 < 0)) {
                    REFINE(rloc0 + 8, a[4]) REFINE(rloc0 + 9, a[5])
                    REFINE(rloc0 + 10, a[6]) REFINE(rloc0 + 11, a[7])
                }
                if (__any((int)g2 < 0)) {
                    REFINE(rloc0 + 16, a[8]) REFINE(rloc0 + 17, a[9])
                    REFINE(rloc0 + 18, a[10]) REFINE(rloc0 + 19, a[11])
                }
                if (__any((int)g3 < 0)) {
                    REFINE(rloc0 + 24, a[12]) REFINE(rloc0 + 25, a[13])
                    REFINE(rloc0 + 26, a[14]) REFINE(rloc0 + 27, a[15])
                }
            }
            c0 = c1; c1 = nx;
        }
    }
#undef FU
#undef REFINE

    __syncthreads();
    if (t < 128)
        idx[b * N_ + rowbase + t] = (int)(u32)(cand[t] & 0xFFFFFFFFu);
}

// ------------------------------------------- transpose known_feats -> (b,m,c) bf16
__global__ __launch_bounds__(256) void k_tr_kf(const float* __restrict__ kf,
                                               u16* __restrict__ kfT) {
    __shared__ float lt[64][65];
    const int t = threadIdx.x, b = blockIdx.z;
    const int j0 = blockIdx.x * 64, c0 = blockIdx.y * 64;
    const int jl = t & 63, cl4 = t >> 6;
#pragma unroll
    for (int p = 0; p < 16; ++p) {
        int c = c0 + cl4 + p * 4;
        lt[cl4 + p * 4][jl] = kf[((size_t)(b * C2_ + c)) * M_ + j0 + jl];
    }
    __syncthreads();
    const int cl = t & 63, jr4 = t >> 6;
#pragma unroll
    for (int p = 0; p < 16; ++p) {
        int j = j0 + jr4 + p * 4;
        kfT[((size_t)(b * M_ + j)) * C2_ + c0 + cl] = f2bf(lt[cl][jr4 + p * 4]);
    }
}

// --------------------------- transpose unknow_feats -> dense ufT (b,n,128) bf16
__global__ __launch_bounds__(256) void k_tr_uf(const float* __restrict__ uf,
                                               u16* __restrict__ ufT) {
    __shared__ float lt[64][65];
    const int t = threadIdx.x, b = blockIdx.z;
    const int i0 = blockIdx.x * 64, c0 = blockIdx.y * 64;
    const int il = t & 63, cl4 = t >> 6;
#pragma unroll
    for (int p = 0; p < 16; ++p) {
        int c = c0 + cl4 + p * 4;
        lt[cl4 + p * 4][il] = uf[((size_t)(b * C1_ + c)) * N_ + i0 + il];
    }
    __syncthreads();
    const int cl = t & 63, ir4 = t >> 6;
#pragma unroll
    for (int p = 0; p < 16; ++p) {
        int i = i0 + ir4 + p * 4;
        ufT[((size_t)(b * N_ + i)) * C1_ + c0 + cl] = f2bf(lt[cl][ir4 + p * 4]);
    }
}

// ---------------------------------------------------------------- GEMM1
// y1[b][i][o] (bf16) = [kfT[idx[i]][0:256] ++ ufT[i][0:128]] . w1[o][:]
// (gather fused into A-staging). BN1 stats fused in epilogue.
__global__ __launch_bounds__(256) void k_gemm1(const u16* __restrict__ kfT,
                                               const u16* __restrict__ ufT,
                                               const int* __restrict__ idx,
                                               const float* __restrict__ w1,
                                               u16* __restrict__ y1,
                                               float* __restrict__ bsum,
                                               float* __restrict__ bsq) {
    __shared__ u16 As[128 * 40];
    __shared__ u16 Bs[128 * 40];
    const int t = threadIdx.x, b = blockIdx.z;
    const int i0 = blockIdx.x * 128, o0 = blockIdx.y * 128;
    const int lane = t & 63, wv = t >> 6, wr = wv >> 1, wc = wv & 1;
    const int col = lane & 15, q = lane >> 4;

    const int rA0 = t >> 2, sA0 = t & 3;   // +256 => row+64, same sub
    const int j0 = idx[b * N_ + i0 + rA0];
    const int j1 = idx[b * N_ + i0 + 64 + rA0];
    const u16* kA0 = kfT + ((size_t)(b * M_ + j0)) * C2_ + sA0 * 8;
    const u16* kA1 = kfT + ((size_t)(b * M_ + j1)) * C2_ + sA0 * 8;
    const u16* uA0 = ufT + ((size_t)(b * N_ + i0 + rA0)) * C1_ + sA0 * 8;
    const u16* uA1 = uA0 + (size_t)64 * C1_;
    const float* bS0 = w1 + (size_t)(o0 + rA0) * K1_ + sA0 * 8;
    const float* bS1 = bS0 + (size_t)64 * K1_;
    u16* aD0 = &As[rA0 * 40 + sA0 * 8];
    u16* aD1 = aD0 + 64 * 40;
    u16* bD0 = &Bs[rA0 * 40 + sA0 * 8];
    u16* bD1 = bD0 + 64 * 40;

    f32x4 acc[4][4];
#pragma unroll
    for (int m = 0; m < 4; ++m)
#pragma unroll
        for (int n = 0; n < 4; ++n) acc[m][n] = (f32x4){0.f, 0.f, 0.f, 0.f};

    uint4 a0 = *(const uint4*)kA0, a1 = *(const uint4*)kA1;
    float4 f00 = *(const float4*)bS0, f01 = *(const float4*)(bS0 + 4);
    float4 f10 = *(const float4*)bS1, f11 = *(const float4*)(bS1 + 4);

    for (int ks = 0; ks < 12; ++ks) {
        __syncthreads();
        *(uint4*)aD0 = a0; *(uint4*)aD1 = a1;
        *(uint4*)bD0 = pack8(f00, f01); *(uint4*)bD1 = pack8(f10, f11);
        __syncthreads();
        if (ks < 11) {
            int kn = ks + 1;
            if (kn < 8) {                 // cols 0..255 from gathered kfT rows
                a0 = *(const uint4*)(kA0 + kn * 32);
                a1 = *(const uint4*)(kA1 + kn * 32);
            } else {                      // cols 256..383 from ufT
                a0 = *(const uint4*)(uA0 + (kn - 8) * 32);
                a1 = *(const uint4*)(uA1 + (kn - 8) * 32);
            }
            int ko = kn * 32;
            f00 = *(const float4*)(bS0 + ko); f01 = *(const float4*)(bS0 + ko + 4);
            f10 = *(const float4*)(bS1 + ko); f11 = *(const float4*)(bS1 + ko + 4);
        }
        const u16* ap = &As[(wr * 64 + col) * 40 + q * 8];
        const u16* bp = &Bs[(wc * 64 + col) * 40 + q * 8];
        bf16x8 af[4], bfr[4];
#pragma unroll
        for (int m = 0; m < 4; ++m) af[m] = *(const bf16x8*)(ap + m * 640);
#pragma unroll
        for (int n = 0; n < 4; ++n) bfr[n] = *(const bf16x8*)(bp + n * 640);
#pragma unroll
        for (int m = 0; m < 4; ++m)
#pragma unroll
            for (int n = 0; n < 4; ++n)
                acc[m][n] = __builtin_amdgcn_mfma_f32_16x16x32_bf16(af[m], bfr[n], acc[m][n], 0, 0, 0);
    }
    float ssum[4], ssq[4];
#pragma unroll
    for (int n = 0; n < 4; ++n) { ssum[n] = 0.f; ssq[n] = 0.f; }
#pragma unroll
    for (int m = 0; m < 4; ++m)
#pragma unroll
        for (int n = 0; n < 4; ++n) {
            int go = o0 + wc * 64 + n * 16 + col;
#pragma unroll
            for (int r = 0; r < 4; ++r) {
                int gi = i0 + wr * 64 + m * 16 + q * 4 + r;
                u16 hv = f2bf(acc[m][n][r]);
                y1[((size_t)(b * N_ + gi)) * O1_ + go] = hv;
                float v = bf2f(hv);
                ssum[n] += v; ssq[n] = fmaf(v, v, ssq[n]);
            }
        }
#pragma unroll
    for (int n = 0; n < 4; ++n) {
        float s = ssum[n], qv = ssq[n];
        s += __shfl_xor(s, 16); qv += __shfl_xor(qv, 16);
        s += __shfl_xor(s, 32); qv += __shfl_xor(qv, 32);
        if (q == 0) {
            int go = o0 + wc * 64 + n * 16 + col;
            atomicAdd(&bsum[go], s);
            atomicAdd(&bsq[go], qv);
        }
    }
}

__global__ void k_bn_fin(const float* __restrict__ sum, const float* __restrict__ sq,
                         const float* __restrict__ gamma, const float* __restrict__ beta,
                         float* __restrict__ scale, float* __restrict__ bias,
                         int C, float invN) {
    int t = threadIdx.x;
    if (t < C) {
        float mean = sum[t] * invN;
        float var = sq[t] * invN - mean * mean;
        float rs = rsqrtf(var + 1e-5f);
        float sc = gamma[t] * rs;
        scale[t] = sc;
        bias[t] = beta[t] - mean * sc;
    }
}

// ---------------------------------------------------------------- GEMM2
// y2[b][i][o] (f32) = relu(bn1(y1))[b][i][:] . w2[o][:]  (BN1 fused in A-staging)
// BN2 stats fused in epilogue (on the raw f32 values)
__global__ __launch_bounds__(256) void k_gemm2(const u16* __restrict__ y1,
                                               const float* __restrict__ w2,
                                               const float* __restrict__ s1,
                                               const float* __restrict__ b1,
                                               float* __restrict__ y2,
                                               float* __restrict__ bsum,
                                               float* __restrict__ bsq) {
    __shared__ u16 As[128 * 40];
    __shared__ u16 Bs[128 * 40];
    const int t = threadIdx.x, b = blockIdx.z;
    const int i0 = blockIdx.x * 128;
    const int lane = t & 63, wv = t >> 6, wr = wv >> 1, wc = wv & 1;
    const int col = lane & 15, q = lane >> 4;

    const int rA0 = t >> 2, sA0 = t & 3;
    const u16* aS0 = y1 + ((size_t)(b * N_ + i0 + rA0)) * O1_ + sA0 * 8;
    const u16* aS1 = aS0 + (size_t)64 * O1_;
    const float* bS0 = w2 + (size_t)rA0 * O1_ + sA0 * 8;
    const float* bS1 = bS0 + (size_t)64 * O1_;
    u16* aD0 = &As[rA0 * 40 + sA0 * 8];
    u16* aD1 = aD0 + 64 * 40;
    u16* bD0 = &Bs[rA0 * 40 + sA0 * 8];
    u16* bD1 = bD0 + 64 * 40;

    f32x4 acc[4][4];
#pragma unroll
    for (int m = 0; m < 4; ++m)
#pragma unroll
        for (int n = 0; n < 4; ++n) acc[m][n] = (f32x4){0.f, 0.f, 0.f, 0.f};

    uint4 a0 = *(const uint4*)aS0, a1 = *(const uint4*)aS1;
    float4 f00 = *(const float4*)bS0, f01 = *(const float4*)(bS0 + 4);
    float4 f10 = *(const float4*)bS1, f11 = *(const float4*)(bS1 + 4);

    for (int ks = 0; ks < 8; ++ks) {
        int oc = ks * 32 + sA0 * 8;
        float4 sc0 = *(const float4*)(s1 + oc), sc1 = *(const float4*)(s1 + oc + 4);
        float4 bb0 = *(const float4*)(b1 + oc), bb1 = *(const float4*)(b1 + oc + 4);
        uint4 h0, h1;
        {
            const u16* hs = (const u16*)&a0;
            float v[8];
            v[0] = fmaxf(fmaf(bf2f(hs[0]), sc0.x, bb0.x), 0.f);
            v[1] = fmaxf(fmaf(bf2f(hs[1]), sc0.y, bb0.y), 0.f);
            v[2] = fmaxf(fmaf(bf2f(hs[2]), sc0.z, bb0.z), 0.f);
            v[3] = fmaxf(fmaf(bf2f(hs[3]), sc0.w, bb0.w), 0.f);
            v[4] = fmaxf(fmaf(bf2f(hs[4]), sc1.x, bb1.x), 0.f);
            v[5] = fmaxf(fmaf(bf2f(hs[5]), sc1.y, bb1.y), 0.f);
            v[6] = fmaxf(fmaf(bf2f(hs[6]), sc1.z, bb1.z), 0.f);
            v[7] = fmaxf(fmaf(bf2f(hs[7]), sc1.w, bb1.w), 0.f);
            h0.x = pack2(v[0], v[1]); h0.y = pack2(v[2], v[3]);
            h0.z = pack2(v[4], v[5]); h0.w = pack2(v[6], v[7]);
        }
        {
            const u16* hs = (const u16*)&a1;
            float v[8];
            v[0] = fmaxf(fmaf(bf2f(hs[0]), sc0.x, bb0.x), 0.f);
            v[1] = fmaxf(fmaf(bf2f(hs[1]), sc0.y, bb0.y), 0.f);
            v[2] = fmaxf(fmaf(bf2f(hs[2]), sc0.z, bb0.z), 0.f);
            v[3] = fmaxf(fmaf(bf2f(hs[3]), sc0.w, bb0.w), 0.f);
            v[4] = fmaxf(fmaf(bf2f(hs[4]), sc1.x, bb1.x), 0.f);
            v[5] = fmaxf(fmaf(bf2f(hs[5]), sc1.y, bb1.y), 0.f);
            v[6] = fmaxf(fmaf(bf2f(hs[6]), sc1.z, bb1.z), 0.f);
            v[7] = fmaxf(fmaf(bf2f(hs[7]), sc1.w, bb1.w), 0.f);
            h1.x = pack2(v[0], v[1]); h1.y = pack2(v[2], v[3]);
            h1.z = pack2(v[4], v[5]); h1.w = pack2(v[6], v[7]);
        }
        __syncthreads();
        *(uint4*)aD0 = h0; *(uint4*)aD1 = h1;
        *(uint4*)bD0 = pack8(f00, f01); *(uint4*)bD1 = pack8(f10, f11);
        __syncthreads();
        if (ks < 7) {
            int ko = (ks + 1) * 32;
            a0 = *(const uint4*)(aS0 + ko); a1 = *(const uint4*)(aS1 + ko);
            f00 = *(const float4*)(bS0 + ko); f01 = *(const float4*)(bS0 + ko + 4);
            f10 = *(const float4*)(bS1 + ko); f11 = *(const float4*)(bS1 + ko + 4);
        }
        const u16* ap = &As[(wr * 64 + col) * 40 + q * 8];
        const u16* bp = &Bs[(wc * 64 + col) * 40 + q * 8];
        bf16x8 af[4], bfr[4];
#pragma unroll
        for (int m = 0; m < 4; ++m) af[m] = *(const bf16x8*)(ap + m * 640);
#pragma unroll
        for (int n = 0; n < 4; ++n) bfr[n] = *(const bf16x8*)(bp + n * 640);
#pragma unroll
        for (int m = 0; m < 4; ++m)
#pragma unroll
            for (int n = 0; n < 4; ++n)
                acc[m][n] = __builtin_amdgcn_mfma_f32_16x16x32_bf16(af[m], bfr[n], acc[m][n], 0, 0, 0);
    }
    float ssum[4], ssq[4];
#pragma unroll
    for (int n = 0; n < 4; ++n) { ssum[n] = 0.f; ssq[n] = 0.f; }
#pragma unroll
    for (int m = 0; m < 4; ++m)
#pragma unroll
        for (int n = 0; n < 4; ++n) {
            int go = wc * 64 + n * 16 + col;
#pragma unroll
            for (int r = 0; r < 4; ++r) {
                int gi = i0 + wr * 64 + m * 16 + q * 4 + r;
                float v = acc[m][n][r];
                y2[((size_t)(b * N_ + gi)) * O2_ + go] = v;
                ssum[n] += v; ssq[n] = fmaf(v, v, ssq[n]);
            }
        }
#pragma unroll
    for (int n = 0; n < 4; ++n) {
        float s = ssum[n], qv = ssq[n];
        s += __shfl_xor(s, 16); qv += __shfl_xor(qv, 16);
        s += __shfl_xor(s, 32); qv += __shfl_xor(qv, 32);
        if (q == 0) {
            int go = wc * 64 + n * 16 + col;
            atomicAdd(&bsum[go], s);
            atomicAdd(&bsq[go], qv);
        }
    }
}

// ---------------------------- BN2 affine + ReLU + transpose (b,i,o)->(b,o,i) out
__global__ __launch_bounds__(256) void k_out(const float* __restrict__ y2,
                                             const float* __restrict__ s2,
                                             const float* __restrict__ b2,
                                             float* __restrict__ out) {
    __shared__ float lt[64 * 65];
    const int t = threadIdx.x, b = blockIdx.z;
    const int i0 = blockIdx.x * 64, o0 = blockIdx.y * 64;
    const int oc = t & 63, ir4 = t >> 6;
    const float sc = s2[o0 + oc], bs = b2[o0 + oc];
#pragma unroll
    for (int p = 0; p < 16; ++p) {
        int i = i0 + ir4 + p * 4;
        float v = y2[((size_t)(b * N_ + i)) * O2_ + o0 + oc];
        lt[oc * 65 + ir4 + p * 4] = fmaxf(fmaf(v, sc, bs), 0.f);
    }
    __syncthreads();
    const int il = t & 63, or4 = t >> 6;
#pragma unroll
    for (int p = 0; p < 16; ++p) {
        int o = o0 + or4 + p * 4;
        out[((size_t)(b * O2_ + o)) * N_ + i0 + il] = lt[(or4 + p * 4) * 65 + il];
    }
}

extern "C" void kernel_launch(void* const* d_in, const int* in_sizes, int n_in,
                              void* d_out, int out_size, void* d_ws, size_t ws_size,
                              hipStream_t stream) {
    const float* unknown = (const float*)d_in[0];
    const float* known   = (const float*)d_in[1];
    const float* uf      = (const float*)d_in[2];
    const float* kf      = (const float*)d_in[3];
    const float* w1      = (const float*)d_in[4];
    const float* g1      = (const float*)d_in[5];
    const float* be1     = (const float*)d_in[6];
    const float* w2      = (const float*)d_in[7];
    const float* g2      = (const float*)d_in[8];
    const float* be2     = (const float*)d_in[9];
    float* out = (float*)d_out;

    char* w = (char*)d_ws;
    // stats block (zeroed each call): bn1_sum[256] bn1_sq[256] bn2_sum[128] bn2_sq[128]
    float* bn1_sum = (float*)w;
    float* bn1_sq  = bn1_sum + 256;
    float* bn2_sum = bn1_sq + 256;
    float* bn2_sq  = bn2_sum + 128;
    float* s1 = (float*)(w + 4096);     // 256
    float* b1 = s1 + 256;               // 256
    float* s2 = b1 + 256;               // 128
    float* b2 = s2 + 128;               // 128
    int* idx = (int*)(w + 8192);                        // 512 KiB -> ends 532480
    u16* ufT = (u16*)(w + 532480);                      // (B,n,128) bf16 = 33.5 MB
    size_t A1 = 532480 + 33554432ULL;
    u16* y1  = (u16*)(w + A1);                          // (B,n,256) bf16 = 67 MB
    size_t A2 = A1 + 67108864ULL;
    u16* kfT = (u16*)(w + A2);                          // (B,m,256) bf16 = 16.7 MB
    size_t A3 = A2 + 16777216ULL;
    u16* Aprep = (u16*)(w + A3);                        // 4 MiB
    u16* Bprep = (u16*)(w + A3 + 4194304ULL);           // 1 MiB
    float4* kco = (float4*)(w + A3 + 5242880ULL);       // 512 KiB
    size_t A4 = A3 + 5767168ULL;
    float* y2 = (float*)(w + A4);                       // (B,n,128) f32 = 67 MB

    hipMemsetAsync(w, 0, 3072, stream);   // zero BN accumulators

    k_prep_u<<<512, 256, 0, stream>>>(unknown, Aprep);
    k_prep_k<<<128, 256, 0, stream>>>(known, Bprep, kco);
    k_nn<<<dim3(N_ / 128, B_), 256, 0, stream>>>(Aprep, Bprep, unknown, kco, idx);
    k_tr_kf<<<dim3(256, 4, 2), 256, 0, stream>>>(kf, kfT);
    k_tr_uf<<<dim3(1024, 2, 2), 256, 0, stream>>>(uf, ufT);
    k_gemm1<<<dim3(512, 2, 2), 256, 0, stream>>>(kfT, ufT, idx, w1, y1, bn1_sum, bn1_sq);
    k_bn_fin<<<1, 256, 0, stream>>>(bn1_sum, bn1_sq, g1, be1, s1, b1, 256, 1.f / 131072.f);
    k_gemm2<<<dim3(512, 1, 2), 256, 0, stream>>>(y1, w2, s1, b1, y2, bn2_sum, bn2_sq);
    k_bn_fin<<<1, 256, 0, stream>>>(bn2_sum, bn2_sq, g2, be2, s2, b2, 128, 1.f / 131072.f);
    k_out<<<dim3(1024, 2, 2), 256, 0, stream>>>(y2, s2, b2, out);
}